// Round 3
// baseline (367.542 us; speedup 1.0000x reference)
//
#include <hip/hip_runtime.h>
#include <hip/hip_bf16.h>

// CrossAttention: q = q_in@Wq+bq; k = k_v@Wk+bk; v = k_v@Wv+bv
// S = q@k^T * EMBED^-0.5 ; P = softmax(S) ; out = P@v
// B=8, I=J=2048, D=1024. All f32 in/out; internal compute bf16 MFMA.

#define BATCH 8
#define SEQ   2048
#define EMB   1024
#define SC2   0.045084222f         // EMB^-0.5 * log2(e)

typedef __attribute__((ext_vector_type(8))) short bf16x8;
typedef __attribute__((ext_vector_type(4))) float f32x4;
typedef __attribute__((ext_vector_type(4))) unsigned short u16x4;
typedef __attribute__((ext_vector_type(8))) unsigned short u16x8;
typedef __attribute__((ext_vector_type(4))) float fl4;

__device__ __forceinline__ unsigned short f2bf(float f) {
    unsigned u = __builtin_bit_cast(unsigned, f);
    unsigned r = u + 0x7fffu + ((u >> 16) & 1u);   // RNE
    return (unsigned short)(r >> 16);
}
__device__ __forceinline__ float bf2f(unsigned short s) {
    return __builtin_bit_cast(float, ((unsigned)s) << 16);
}
__device__ __forceinline__ void gload16(const unsigned short* g, unsigned short* l) {
    __builtin_amdgcn_global_load_lds(
        (const __attribute__((address_space(1))) void*)g,
        (__attribute__((address_space(3))) void*)l, 16, 0, 0);
}

// ---------------------------------------------------------------------------
// Convert f32 inputs -> bf16 (q_in -> qbin, k_v -> kvbin)
// ---------------------------------------------------------------------------
__global__ __launch_bounds__(256)
void convert_in(const float* __restrict__ q_in, const float* __restrict__ k_v,
                unsigned short* __restrict__ qbin, unsigned short* __restrict__ kvbin)
{
    const size_t N = (size_t)BATCH * SEQ * EMB;   // 16777216
    size_t idx = ((size_t)blockIdx.x * 256 + threadIdx.x) * 8;
    const size_t stride = (size_t)gridDim.x * 256 * 8;
    for (; idx < N; idx += stride) {
        fl4 a0 = *(const fl4*)&q_in[idx];
        fl4 a1 = *(const fl4*)&q_in[idx + 4];
        fl4 b0 = *(const fl4*)&k_v[idx];
        fl4 b1 = *(const fl4*)&k_v[idx + 4];
        u16x8 ua, ub;
#pragma unroll
        for (int i = 0; i < 4; i++) {
            ua[i] = f2bf(a0[i]); ua[i + 4] = f2bf(a1[i]);
            ub[i] = f2bf(b0[i]); ub[i + 4] = f2bf(b1[i]);
        }
        *(u16x8*)&qbin[idx] = ua;
        *(u16x8*)&kvbin[idx] = ub;
    }
}

// ---------------------------------------------------------------------------
// Convert + transpose W [k][n] f32 -> Wt [n][k] bf16 (3 weights concatenated)
// ---------------------------------------------------------------------------
__global__ __launch_bounds__(256)
void convert_w(const float* __restrict__ Wq, const float* __restrict__ Wk,
               const float* __restrict__ Wv, unsigned short* __restrict__ Wt)
{
    const int wsel = blockIdx.y;
    const float* W = (wsel == 0) ? Wq : (wsel == 1) ? Wk : Wv;
    unsigned short* O = Wt + (size_t)wsel * EMB * EMB;
    const int k0 = (blockIdx.x >> 4) * 64;
    const int n0 = (blockIdx.x & 15) * 64;
    __shared__ unsigned short l[64 * 65];
    const int tid = threadIdx.x;
#pragma unroll
    for (int it = 0; it < 16; it++) {
        const int lin = it * 256 + tid;
        const int k = lin >> 6, n = lin & 63;
        l[n * 65 + k] = f2bf(W[(size_t)(k0 + k) * EMB + n0 + n]);
    }
    __syncthreads();
#pragma unroll
    for (int it = 0; it < 16; it++) {
        const int lin = it * 256 + tid;
        const int n = lin >> 6, k = lin & 63;
        O[(size_t)(n0 + n) * EMB + k0 + k] = l[n * 65 + k];
    }
}

// ---------------------------------------------------------------------------
// proj_q: O = X @ Wt^T + bias (all bf16, K-contiguous both operands)
// m97 structure: 128x128 tile, BK=64, global_load_lds(16B), linear LDS.
// ---------------------------------------------------------------------------
__global__ __launch_bounds__(256, 2)
void proj_q_kernel(const unsigned short* __restrict__ X,
                   const unsigned short* __restrict__ Wt,
                   const float* __restrict__ bias,
                   unsigned short* __restrict__ O)
{
    const int bid = blockIdx.x;
    const int mt = ((bid >> 6) << 3) | (bid & 7);   // XCD-grouped M-tiles
    const int nt = (bid >> 3) & 7;
    const int m0 = mt * 128, n0 = nt * 128;

    __shared__ unsigned short lA[128 * 64];
    __shared__ unsigned short lB[128 * 64];

    const int tid = threadIdx.x, lane = tid & 63;
    const int w = tid >> 6, wr = w >> 1, wc = w & 1;
    const int r = lane & 15, g = lane >> 4;
    const int srow = lane >> 3, scol = lane & 7;

    f32x4 acc[4][4];
#pragma unroll
    for (int i = 0; i < 4; i++)
#pragma unroll
        for (int j = 0; j < 4; j++) acc[i][j] = (f32x4)0.0f;

    for (int k0 = 0; k0 < EMB; k0 += 64) {
        __syncthreads();
#pragma unroll
        for (int i = 0; i < 4; i++) {
            const int c = w * 4 + i;           // chunk of 8 rows
            const int row = c * 8 + srow;
            gload16(&X[(size_t)(m0 + row) * EMB + k0 + scol * 8], &lA[c * 512]);
            gload16(&Wt[(size_t)(n0 + row) * EMB + k0 + scol * 8], &lB[c * 512]);
        }
        __syncthreads();
#pragma unroll
        for (int kk = 0; kk < 2; kk++) {
            bf16x8 af[4], bf[4];
#pragma unroll
            for (int m = 0; m < 4; m++)
                af[m] = *(bf16x8*)&lA[(wr * 64 + m * 16 + r) * 64 + kk * 32 + g * 8];
#pragma unroll
            for (int n = 0; n < 4; n++)
                bf[n] = *(bf16x8*)&lB[(wc * 64 + n * 16 + r) * 64 + kk * 32 + g * 8];
#pragma unroll
            for (int m = 0; m < 4; m++)
#pragma unroll
                for (int n = 0; n < 4; n++)
                    acc[m][n] = __builtin_amdgcn_mfma_f32_16x16x32_bf16(af[m], bf[n], acc[m][n], 0, 0, 0);
        }
    }

#pragma unroll
    for (int n = 0; n < 4; n++) {
        const int col = n0 + wc * 64 + n * 16 + r;
        const float bb = bias[col];
#pragma unroll
        for (int m = 0; m < 4; m++) {
            const int rowb = m0 + wr * 64 + m * 16 + g * 4;
#pragma unroll
            for (int i = 0; i < 4; i++)
                O[(size_t)(rowb + i) * EMB + col] = f2bf(acc[m][n][i] + bb);
        }
    }
}

// ---------------------------------------------------------------------------
// proj_kv: k = X@Wkt^T+bk -> kb [m][d]; v = X@Wvt^T+bv -> vt [b][d][j]
// Shares the A (k_v) staging between both outputs.
// ---------------------------------------------------------------------------
__global__ __launch_bounds__(256, 2)
void proj_kv_kernel(const unsigned short* __restrict__ X,
                    const unsigned short* __restrict__ Wkt,
                    const unsigned short* __restrict__ Wvt,
                    const float* __restrict__ bk, const float* __restrict__ bv,
                    unsigned short* __restrict__ kb, unsigned short* __restrict__ vt)
{
    const int bid = blockIdx.x;
    const int mt = ((bid >> 6) << 3) | (bid & 7);
    const int nt = (bid >> 3) & 7;
    const int m0 = mt * 128, n0 = nt * 128;

    __shared__ unsigned short lA[128 * 64];
    __shared__ unsigned short lBk[128 * 64];
    __shared__ unsigned short lBv[128 * 64];

    const int tid = threadIdx.x, lane = tid & 63;
    const int w = tid >> 6, wr = w >> 1, wc = w & 1;
    const int r = lane & 15, g = lane >> 4;
    const int srow = lane >> 3, scol = lane & 7;

    f32x4 acck[4][4], accv[4][4];
#pragma unroll
    for (int i = 0; i < 4; i++)
#pragma unroll
        for (int j = 0; j < 4; j++) { acck[i][j] = (f32x4)0.0f; accv[i][j] = (f32x4)0.0f; }

    for (int k0 = 0; k0 < EMB; k0 += 64) {
        __syncthreads();
#pragma unroll
        for (int i = 0; i < 4; i++) {
            const int c = w * 4 + i;
            const int row = c * 8 + srow;
            const size_t goff = (size_t)row * EMB + k0 + scol * 8;
            gload16(&X[(size_t)m0 * EMB + goff], &lA[c * 512]);
            gload16(&Wkt[(size_t)n0 * EMB + goff], &lBk[c * 512]);
            gload16(&Wvt[(size_t)n0 * EMB + goff], &lBv[c * 512]);
        }
        __syncthreads();
#pragma unroll
        for (int kk = 0; kk < 2; kk++) {
            bf16x8 af[4], bfk[4], bfv[4];
#pragma unroll
            for (int m = 0; m < 4; m++)
                af[m] = *(bf16x8*)&lA[(wr * 64 + m * 16 + r) * 64 + kk * 32 + g * 8];
#pragma unroll
            for (int n = 0; n < 4; n++) {
                bfk[n] = *(bf16x8*)&lBk[(wc * 64 + n * 16 + r) * 64 + kk * 32 + g * 8];
                bfv[n] = *(bf16x8*)&lBv[(wc * 64 + n * 16 + r) * 64 + kk * 32 + g * 8];
            }
#pragma unroll
            for (int m = 0; m < 4; m++)
#pragma unroll
                for (int n = 0; n < 4; n++) {
                    acck[m][n] = __builtin_amdgcn_mfma_f32_16x16x32_bf16(af[m], bfk[n], acck[m][n], 0, 0, 0);
                    accv[m][n] = __builtin_amdgcn_mfma_f32_16x16x32_bf16(af[m], bfv[n], accv[m][n], 0, 0, 0);
                }
        }
    }

    const int b = m0 >> 11;              // batch of this 128-row tile
    const int j0 = m0 & 2047;
#pragma unroll
    for (int n = 0; n < 4; n++) {
        const int col = n0 + wc * 64 + n * 16 + r;
        const float bbk = bk[col];
        const float bbv = bv[col];
#pragma unroll
        for (int m = 0; m < 4; m++) {
            const int rowb = m0 + wr * 64 + m * 16 + g * 4;
#pragma unroll
            for (int i = 0; i < 4; i++)
                kb[(size_t)(rowb + i) * EMB + col] = f2bf(acck[m][n][i] + bbk);
            // v transposed: vt[b][d=col][j]
            const int j = j0 + wr * 64 + m * 16 + g * 4;
            u16x4 u;
#pragma unroll
            for (int i = 0; i < 4; i++) u[i] = f2bf(accv[m][n][i] + bbv);
            *(u16x4*)&vt[((size_t)b * EMB + col) * SEQ + j] = u;
        }
    }
}

// ---------------------------------------------------------------------------
// qk: P = exp2(qb @ kb^T * sc)  (m97 gload_lds structure)
// Also emits deterministic partial rowsums: Ppart[jt*2+wc][b*SEQ+i].
// ---------------------------------------------------------------------------
__global__ __launch_bounds__(256, 2)
void qk_kernel(const unsigned short* __restrict__ qb,
               const unsigned short* __restrict__ kb,
               unsigned short* __restrict__ P,
               float* __restrict__ Ppart)
{
    const int b = blockIdx.z;
    const int m0 = blockIdx.x * 128;   // i
    const int n0 = blockIdx.y * 128;   // j
    const unsigned short* Aq = qb + (size_t)b * SEQ * EMB;
    const unsigned short* Bk = kb + (size_t)b * SEQ * EMB;

    __shared__ unsigned short lA[128 * 64];
    __shared__ unsigned short lB[128 * 64];

    const int tid = threadIdx.x, lane = tid & 63;
    const int w = tid >> 6, wr = w >> 1, wc = w & 1;
    const int r = lane & 15, g = lane >> 4;
    const int srow = lane >> 3, scol = lane & 7;

    f32x4 acc[4][4];
#pragma unroll
    for (int i = 0; i < 4; i++)
#pragma unroll
        for (int j = 0; j < 4; j++) acc[i][j] = (f32x4)0.0f;

    for (int k0 = 0; k0 < EMB; k0 += 64) {
        __syncthreads();
#pragma unroll
        for (int i = 0; i < 4; i++) {
            const int c = w * 4 + i;
            const int row = c * 8 + srow;
            gload16(&Aq[(size_t)(m0 + row) * EMB + k0 + scol * 8], &lA[c * 512]);
            gload16(&Bk[(size_t)(n0 + row) * EMB + k0 + scol * 8], &lB[c * 512]);
        }
        __syncthreads();
#pragma unroll
        for (int kk = 0; kk < 2; kk++) {
            bf16x8 af[4], bfv[4];
#pragma unroll
            for (int m = 0; m < 4; m++)
                af[m] = *(bf16x8*)&lA[(wr * 64 + m * 16 + r) * 64 + kk * 32 + g * 8];
#pragma unroll
            for (int n = 0; n < 4; n++)
                bfv[n] = *(bf16x8*)&lB[(wc * 64 + n * 16 + r) * 64 + kk * 32 + g * 8];
#pragma unroll
            for (int m = 0; m < 4; m++)
#pragma unroll
                for (int n = 0; n < 4; n++)
                    acc[m][n] = __builtin_amdgcn_mfma_f32_16x16x32_bf16(af[m], bfv[n], acc[m][n], 0, 0, 0);
        }
    }

    unsigned short* Pb = P + (size_t)b * SEQ * SEQ;
    float ps[4][4];   // [m][i] partial row sums over this wave's 64 j-cols
#pragma unroll
    for (int m = 0; m < 4; m++)
#pragma unroll
        for (int i = 0; i < 4; i++) ps[m][i] = 0.f;

#pragma unroll
    for (int m = 0; m < 4; m++) {
        const int ib = m0 + wr * 64 + m * 16 + g * 4;
#pragma unroll
        for (int n = 0; n < 4; n++) {
            const int j = n0 + wc * 64 + n * 16 + r;
#pragma unroll
            for (int i = 0; i < 4; i++) {
                const float p = exp2f(acc[m][n][i] * SC2);   // no max-sub: |S|<~6
                ps[m][i] += p;
                Pb[(size_t)(ib + i) * SEQ + j] = f2bf(p);
            }
        }
    }
    // reduce ps across the 16-lane r-group (sums 64 j-cols of this wave)
#pragma unroll
    for (int off = 1; off < 16; off <<= 1)
#pragma unroll
        for (int m = 0; m < 4; m++)
#pragma unroll
            for (int i = 0; i < 4; i++)
                ps[m][i] += __shfl_xor(ps[m][i], off);
    if (r == 0) {
        const int slot = blockIdx.y * 2 + wc;
        float* pp = Ppart + (size_t)slot * (BATCH * SEQ) + (size_t)b * SEQ;
#pragma unroll
        for (int m = 0; m < 4; m++) {
            const int row = m0 + wr * 64 + m * 16 + g * 4;
#pragma unroll
            for (int i = 0; i < 4; i++) pp[row + i] = ps[m][i];
        }
    }
}

// ---------------------------------------------------------------------------
// rowsum finalize: rs[row] = sum over 32 slots of Ppart
// ---------------------------------------------------------------------------
__global__ __launch_bounds__(256)
void rowsum_final(const float* __restrict__ Ppart, float* __restrict__ rs)
{
    const int row = blockIdx.x * 256 + threadIdx.x;   // 16384 rows
    float s = 0.f;
#pragma unroll
    for (int slot = 0; slot < 32; slot++)
        s += Ppart[(size_t)slot * (BATCH * SEQ) + row];
    rs[row] = s;
}

// ---------------------------------------------------------------------------
// pv: out = (P @ v) / rowsum  (m97 gload_lds structure)
// A = P [i][j] (K=j contig, stride SEQ), B = vt [d][j] (K=j contig).
// ---------------------------------------------------------------------------
__global__ __launch_bounds__(256, 2)
void pv_kernel(const unsigned short* __restrict__ P,
               const unsigned short* __restrict__ vt,
               const float* __restrict__ rs,
               float* __restrict__ out)
{
    const int b = blockIdx.z;
    const int m0 = blockIdx.x * 128;   // i
    const int n0 = blockIdx.y * 128;   // d
    const unsigned short* Ap = P  + (size_t)b * SEQ * SEQ;
    const unsigned short* Bv = vt + (size_t)b * EMB * SEQ;

    __shared__ unsigned short lA[128 * 64];
    __shared__ unsigned short lB[128 * 64];

    const int tid = threadIdx.x, lane = tid & 63;
    const int w = tid >> 6, wr = w >> 1, wc = w & 1;
    const int r = lane & 15, g = lane >> 4;
    const int srow = lane >> 3, scol = lane & 7;

    f32x4 acc[4][4];
#pragma unroll
    for (int i = 0; i < 4; i++)
#pragma unroll
        for (int j = 0; j < 4; j++) acc[i][j] = (f32x4)0.0f;

    for (int k0 = 0; k0 < SEQ; k0 += 64) {
        __syncthreads();
#pragma unroll
        for (int i = 0; i < 4; i++) {
            const int c = w * 4 + i;
            const int row = c * 8 + srow;
            gload16(&Ap[(size_t)(m0 + row) * SEQ + k0 + scol * 8], &lA[c * 512]);
            gload16(&Bv[(size_t)(n0 + row) * SEQ + k0 + scol * 8], &lB[c * 512]);
        }
        __syncthreads();
#pragma unroll
        for (int kk = 0; kk < 2; kk++) {
            bf16x8 af[4], bfv[4];
#pragma unroll
            for (int m = 0; m < 4; m++)
                af[m] = *(bf16x8*)&lA[(wr * 64 + m * 16 + r) * 64 + kk * 32 + g * 8];
#pragma unroll
            for (int n = 0; n < 4; n++)
                bfv[n] = *(bf16x8*)&lB[(wc * 64 + n * 16 + r) * 64 + kk * 32 + g * 8];
#pragma unroll
            for (int m = 0; m < 4; m++)
#pragma unroll
                for (int n = 0; n < 4; n++)
                    acc[m][n] = __builtin_amdgcn_mfma_f32_16x16x32_bf16(af[m], bfv[n], acc[m][n], 0, 0, 0);
        }
    }

    float* ob = out + (size_t)b * SEQ * EMB;
    const float* rsb = rs + (size_t)b * SEQ;
#pragma unroll
    for (int m = 0; m < 4; m++) {
        const int ib = m0 + wr * 64 + m * 16 + g * 4;
#pragma unroll
        for (int i = 0; i < 4; i++) {
            const float inv = 1.0f / rsb[ib + i];
#pragma unroll
            for (int n = 0; n < 4; n++) {
                const int d = n0 + wc * 64 + n * 16 + r;
                ob[(size_t)(ib + i) * EMB + d] = acc[m][n][i] * inv;
            }
        }
    }
}

// ---------------------------------------------------------------------------
extern "C" void kernel_launch(void* const* d_in, const int* in_sizes, int n_in,
                              void* d_out, int out_size, void* d_ws, size_t ws_size,
                              hipStream_t stream)
{
    const float* q_in = (const float*)d_in[0];
    const float* k_v  = (const float*)d_in[1];
    const float* Wq   = (const float*)d_in[2];
    const float* bq   = (const float*)d_in[3];
    const float* Wk   = (const float*)d_in[4];
    const float* bk   = (const float*)d_in[5];
    const float* Wv   = (const float*)d_in[6];
    const float* bv   = (const float*)d_in[7];
    float* out = (float*)d_out;

    // workspace layout (bytes, MB = 1048576):
    //   qbin  bf16 [8][2048][1024] @ 0      (32 MB)  -- dead after proj_q
    //   kvbin bf16 [8][2048][1024] @ 32 MB  (32 MB)  -- dead after proj_kv
    //   P     bf16 [8][2048][2048] @ 0      (64 MB)  -- aliases qbin+kvbin
    //   qb    bf16                 @ 64 MB  (32 MB)
    //   kb    bf16                 @ 96 MB  (32 MB)
    //   vt    bf16 [8][1024][2048] @ 128 MB (32 MB)
    //   Wt    bf16 3x[1024][1024]  @ 160 MB (6 MB)
    //   Ppart f32  [32][16384]     @ 166 MB (2 MB)
    //   rs    f32  [8][2048]       @ 168 MB
    char* ws = (char*)d_ws;
    unsigned short* qbin = (unsigned short*)(ws);
    unsigned short* kvbin= (unsigned short*)(ws + (size_t)33554432);
    unsigned short* P    = (unsigned short*)(ws);
    unsigned short* qb   = (unsigned short*)(ws + (size_t)67108864);
    unsigned short* kb   = (unsigned short*)(ws + (size_t)100663296);
    unsigned short* vt   = (unsigned short*)(ws + (size_t)134217728);
    unsigned short* Wt   = (unsigned short*)(ws + (size_t)167772160);
    float*          Ppart= (float*)(ws + (size_t)174063616);
    float*          rs   = (float*)(ws + (size_t)176160768);

    convert_in<<<4096, 256, 0, stream>>>(q_in, k_v, qbin, kvbin);
    convert_w<<<dim3(256, 3), 256, 0, stream>>>(Wq, Wk, Wv, Wt);
    proj_q_kernel<<<1024, 256, 0, stream>>>(qbin, Wt, bq, qb);
    proj_kv_kernel<<<1024, 256, 0, stream>>>(kvbin, Wt + (size_t)EMB * EMB,
                                             Wt + (size_t)2 * EMB * EMB, bk, bv, kb, vt);
    qk_kernel<<<dim3(16, 16, BATCH), 256, 0, stream>>>(qb, kb, P, Ppart);
    rowsum_final<<<64, 256, 0, stream>>>(Ppart, rs);
    pv_kernel<<<dim3(16, 8, BATCH), 256, 0, stream>>>(P, vt, rs, out);
}

// Round 4
// 329.753 us; speedup vs baseline: 1.1146x; 1.1146x over previous
//
#include <hip/hip_runtime.h>
#include <hip/hip_bf16.h>

// CrossAttention: q = q_in@Wq+bq; k = k_v@Wk+bk; v = k_v@Wv+bv
// S = q@k^T * EMBED^-0.5 ; P = softmax(S) ; out = P@v
// B=8, I=J=2048, D=1024. All f32 in/out; internal compute bf16 MFMA.

#define BATCH 8
#define SEQ   2048
#define EMB   1024
#define SC2   0.045084222f         // EMB^-0.5 * log2(e)

typedef __attribute__((ext_vector_type(8))) short bf16x8;
typedef __attribute__((ext_vector_type(4))) float f32x4;
typedef __attribute__((ext_vector_type(4))) unsigned short u16x4;
typedef __attribute__((ext_vector_type(8))) unsigned short u16x8;
typedef __attribute__((ext_vector_type(4))) float fl4;

__device__ __forceinline__ unsigned short f2bf(float f) {
    unsigned u = __builtin_bit_cast(unsigned, f);
    unsigned r = u + 0x7fffu + ((u >> 16) & 1u);   // RNE
    return (unsigned short)(r >> 16);
}
__device__ __forceinline__ float bf2f(unsigned short s) {
    return __builtin_bit_cast(float, ((unsigned)s) << 16);
}
__device__ __forceinline__ void gload16(const unsigned short* g, unsigned short* l) {
    __builtin_amdgcn_global_load_lds(
        (const __attribute__((address_space(1))) void*)g,
        (__attribute__((address_space(3))) void*)l, 16, 0, 0);
}

// ---------------------------------------------------------------------------
// Convert f32 inputs -> bf16 (q_in -> qbin, k_v -> kvbin)
// ---------------------------------------------------------------------------
__global__ __launch_bounds__(256)
void convert_in(const float* __restrict__ q_in, const float* __restrict__ k_v,
                unsigned short* __restrict__ qbin, unsigned short* __restrict__ kvbin)
{
    const size_t N = (size_t)BATCH * SEQ * EMB;
    size_t idx = ((size_t)blockIdx.x * 256 + threadIdx.x) * 8;
    const size_t stride = (size_t)gridDim.x * 256 * 8;
    for (; idx < N; idx += stride) {
        fl4 a0 = *(const fl4*)&q_in[idx];
        fl4 a1 = *(const fl4*)&q_in[idx + 4];
        fl4 b0 = *(const fl4*)&k_v[idx];
        fl4 b1 = *(const fl4*)&k_v[idx + 4];
        u16x8 ua, ub;
#pragma unroll
        for (int i = 0; i < 4; i++) {
            ua[i] = f2bf(a0[i]); ua[i + 4] = f2bf(a1[i]);
            ub[i] = f2bf(b0[i]); ub[i + 4] = f2bf(b1[i]);
        }
        *(u16x8*)&qbin[idx] = ua;
        *(u16x8*)&kvbin[idx] = ub;
    }
}

// ---------------------------------------------------------------------------
// Convert + transpose W [k][n] f32 -> Wt [n][k] bf16 (3 weights concatenated)
// ---------------------------------------------------------------------------
__global__ __launch_bounds__(256)
void convert_w(const float* __restrict__ Wq, const float* __restrict__ Wk,
               const float* __restrict__ Wv, unsigned short* __restrict__ Wt)
{
    const int wsel = blockIdx.y;
    const float* W = (wsel == 0) ? Wq : (wsel == 1) ? Wk : Wv;
    unsigned short* O = Wt + (size_t)wsel * EMB * EMB;
    const int k0 = (blockIdx.x >> 4) * 64;
    const int n0 = (blockIdx.x & 15) * 64;
    __shared__ unsigned short l[64 * 65];
    const int tid = threadIdx.x;
#pragma unroll
    for (int it = 0; it < 16; it++) {
        const int lin = it * 256 + tid;
        const int k = lin >> 6, n = lin & 63;
        l[n * 65 + k] = f2bf(W[(size_t)(k0 + k) * EMB + n0 + n]);
    }
    __syncthreads();
#pragma unroll
    for (int it = 0; it < 16; it++) {
        const int lin = it * 256 + tid;
        const int n = lin >> 6, k = lin & 63;
        O[(size_t)(n0 + n) * EMB + k0 + k] = l[n * 65 + k];
    }
}

// ---------------------------------------------------------------------------
// proj_q: O = X @ Wt^T + bias (m97 structure, unchanged this round)
// ---------------------------------------------------------------------------
__global__ __launch_bounds__(256, 2)
void proj_q_kernel(const unsigned short* __restrict__ X,
                   const unsigned short* __restrict__ Wt,
                   const float* __restrict__ bias,
                   unsigned short* __restrict__ O)
{
    const int bid = blockIdx.x;
    const int mt = ((bid >> 6) << 3) | (bid & 7);
    const int nt = (bid >> 3) & 7;
    const int m0 = mt * 128, n0 = nt * 128;

    __shared__ unsigned short lA[128 * 64];
    __shared__ unsigned short lB[128 * 64];

    const int tid = threadIdx.x, lane = tid & 63;
    const int w = tid >> 6, wr = w >> 1, wc = w & 1;
    const int r = lane & 15, g = lane >> 4;
    const int srow = lane >> 3, scol = lane & 7;

    f32x4 acc[4][4];
#pragma unroll
    for (int i = 0; i < 4; i++)
#pragma unroll
        for (int j = 0; j < 4; j++) acc[i][j] = (f32x4)0.0f;

    for (int k0 = 0; k0 < EMB; k0 += 64) {
        __syncthreads();
#pragma unroll
        for (int i = 0; i < 4; i++) {
            const int c = w * 4 + i;
            const int row = c * 8 + srow;
            gload16(&X[(size_t)(m0 + row) * EMB + k0 + scol * 8], &lA[c * 512]);
            gload16(&Wt[(size_t)(n0 + row) * EMB + k0 + scol * 8], &lB[c * 512]);
        }
        __syncthreads();
#pragma unroll
        for (int kk = 0; kk < 2; kk++) {
            bf16x8 af[4], bf[4];
#pragma unroll
            for (int m = 0; m < 4; m++)
                af[m] = *(bf16x8*)&lA[(wr * 64 + m * 16 + r) * 64 + kk * 32 + g * 8];
#pragma unroll
            for (int n = 0; n < 4; n++)
                bf[n] = *(bf16x8*)&lB[(wc * 64 + n * 16 + r) * 64 + kk * 32 + g * 8];
#pragma unroll
            for (int m = 0; m < 4; m++)
#pragma unroll
                for (int n = 0; n < 4; n++)
                    acc[m][n] = __builtin_amdgcn_mfma_f32_16x16x32_bf16(af[m], bf[n], acc[m][n], 0, 0, 0);
        }
    }

#pragma unroll
    for (int n = 0; n < 4; n++) {
        const int col = n0 + wc * 64 + n * 16 + r;
        const float bb = bias[col];
#pragma unroll
        for (int m = 0; m < 4; m++) {
            const int rowb = m0 + wr * 64 + m * 16 + g * 4;
#pragma unroll
            for (int i = 0; i < 4; i++)
                O[(size_t)(rowb + i) * EMB + col] = f2bf(acc[m][n][i] + bb);
        }
    }
}

// ---------------------------------------------------------------------------
// proj_kv: unchanged this round
// ---------------------------------------------------------------------------
__global__ __launch_bounds__(256, 2)
void proj_kv_kernel(const unsigned short* __restrict__ X,
                    const unsigned short* __restrict__ Wkt,
                    const unsigned short* __restrict__ Wvt,
                    const float* __restrict__ bk, const float* __restrict__ bv,
                    unsigned short* __restrict__ kb, unsigned short* __restrict__ vt)
{
    const int bid = blockIdx.x;
    const int mt = ((bid >> 6) << 3) | (bid & 7);
    const int nt = (bid >> 3) & 7;
    const int m0 = mt * 128, n0 = nt * 128;

    __shared__ unsigned short lA[128 * 64];
    __shared__ unsigned short lBk[128 * 64];
    __shared__ unsigned short lBv[128 * 64];

    const int tid = threadIdx.x, lane = tid & 63;
    const int w = tid >> 6, wr = w >> 1, wc = w & 1;
    const int r = lane & 15, g = lane >> 4;
    const int srow = lane >> 3, scol = lane & 7;

    f32x4 acck[4][4], accv[4][4];
#pragma unroll
    for (int i = 0; i < 4; i++)
#pragma unroll
        for (int j = 0; j < 4; j++) { acck[i][j] = (f32x4)0.0f; accv[i][j] = (f32x4)0.0f; }

    for (int k0 = 0; k0 < EMB; k0 += 64) {
        __syncthreads();
#pragma unroll
        for (int i = 0; i < 4; i++) {
            const int c = w * 4 + i;
            const int row = c * 8 + srow;
            const size_t goff = (size_t)row * EMB + k0 + scol * 8;
            gload16(&X[(size_t)m0 * EMB + goff], &lA[c * 512]);
            gload16(&Wkt[(size_t)n0 * EMB + goff], &lBk[c * 512]);
            gload16(&Wvt[(size_t)n0 * EMB + goff], &lBv[c * 512]);
        }
        __syncthreads();
#pragma unroll
        for (int kk = 0; kk < 2; kk++) {
            bf16x8 af[4], bfk[4], bfv[4];
#pragma unroll
            for (int m = 0; m < 4; m++)
                af[m] = *(bf16x8*)&lA[(wr * 64 + m * 16 + r) * 64 + kk * 32 + g * 8];
#pragma unroll
            for (int n = 0; n < 4; n++) {
                bfk[n] = *(bf16x8*)&lBk[(wc * 64 + n * 16 + r) * 64 + kk * 32 + g * 8];
                bfv[n] = *(bf16x8*)&lBv[(wc * 64 + n * 16 + r) * 64 + kk * 32 + g * 8];
            }
#pragma unroll
            for (int m = 0; m < 4; m++)
#pragma unroll
                for (int n = 0; n < 4; n++) {
                    acck[m][n] = __builtin_amdgcn_mfma_f32_16x16x32_bf16(af[m], bfk[n], acck[m][n], 0, 0, 0);
                    accv[m][n] = __builtin_amdgcn_mfma_f32_16x16x32_bf16(af[m], bfv[n], accv[m][n], 0, 0, 0);
                }
        }
    }

    const int b = m0 >> 11;
    const int j0 = m0 & 2047;
#pragma unroll
    for (int n = 0; n < 4; n++) {
        const int col = n0 + wc * 64 + n * 16 + r;
        const float bbk = bk[col];
        const float bbv = bv[col];
#pragma unroll
        for (int m = 0; m < 4; m++) {
            const int rowb = m0 + wr * 64 + m * 16 + g * 4;
#pragma unroll
            for (int i = 0; i < 4; i++)
                kb[(size_t)(rowb + i) * EMB + col] = f2bf(acck[m][n][i] + bbk);
            const int j = j0 + wr * 64 + m * 16 + g * 4;
            u16x4 u;
#pragma unroll
            for (int i = 0; i < 4; i++) u[i] = f2bf(accv[m][n][i] + bbv);
            *(u16x4*)&vt[((size_t)b * EMB + col) * SEQ + j] = u;
        }
    }
}

// ---------------------------------------------------------------------------
// Deep-pipelined 256x256 GEMM core pieces (BK=32, 8 waves, 4-slot LDS ring).
// LDS tile layout [256][32] bf16 (rows of 64 B): frag ds_read_b128 is
// aggregate-conflict-free (row stride 64 B = half the 32-bank width).
// Stage: one 16 KB K-tile = 2 issues x 512 thr x 16 B, linear.
// Schedule (proven): tile T staged at phases 2T-3/2T-2, first read 2T+1;
// vmcnt(4)+barrier at end of each tile's phase 2 guarantees next tile's
// stages (all waves) landed while 2 newest stages stay in flight.
// ---------------------------------------------------------------------------
__device__ __forceinline__ void stageT(const unsigned short* lanebase, size_t rstride,
                                       unsigned short* lwave) {
#pragma unroll
    for (int i = 0; i < 2; i++)
        gload16(lanebase + (size_t)(i * 128) * rstride, lwave + i * 4096);
}

#define PIPE_PHASE1(SLOT, DO_STAGE, STAGE_A_BASE, STAGE_A_LDS)                  \
    {                                                                           \
        const unsigned short* pa = &sA[SLOT][0];                                \
        const unsigned short* pb = &sB[SLOT][0];                                \
        bf16x8 a0 = *(bf16x8*)&pa[aoff0];                                       \
        bf16x8 a1 = *(bf16x8*)&pa[aoff0 + 512];                                 \
        bf16x8 a2 = *(bf16x8*)&pa[aoff0 + 1024];                                \
        bf16x8 a3 = *(bf16x8*)&pa[aoff0 + 1536];                                \
        bv0 = *(bf16x8*)&pb[boff0];                                             \
        bv1 = *(bf16x8*)&pb[boff0 + 512];                                       \
        bv2 = *(bf16x8*)&pb[boff0 + 1024];                                      \
        bv3 = *(bf16x8*)&pb[boff0 + 1536];                                      \
        if (DO_STAGE) stageT(STAGE_A_BASE, strideA, STAGE_A_LDS);               \
        __builtin_amdgcn_s_barrier();                                           \
        asm volatile("s_waitcnt lgkmcnt(0)" ::: "memory");                      \
        __builtin_amdgcn_sched_barrier(0);                                      \
        __builtin_amdgcn_s_setprio(1);                                          \
        acc[0][0] = __builtin_amdgcn_mfma_f32_16x16x32_bf16(a0, bv0, acc[0][0], 0, 0, 0); \
        acc[0][1] = __builtin_amdgcn_mfma_f32_16x16x32_bf16(a0, bv1, acc[0][1], 0, 0, 0); \
        acc[0][2] = __builtin_amdgcn_mfma_f32_16x16x32_bf16(a0, bv2, acc[0][2], 0, 0, 0); \
        acc[0][3] = __builtin_amdgcn_mfma_f32_16x16x32_bf16(a0, bv3, acc[0][3], 0, 0, 0); \
        acc[1][0] = __builtin_amdgcn_mfma_f32_16x16x32_bf16(a1, bv0, acc[1][0], 0, 0, 0); \
        acc[1][1] = __builtin_amdgcn_mfma_f32_16x16x32_bf16(a1, bv1, acc[1][1], 0, 0, 0); \
        acc[1][2] = __builtin_amdgcn_mfma_f32_16x16x32_bf16(a1, bv2, acc[1][2], 0, 0, 0); \
        acc[1][3] = __builtin_amdgcn_mfma_f32_16x16x32_bf16(a1, bv3, acc[1][3], 0, 0, 0); \
        acc[2][0] = __builtin_amdgcn_mfma_f32_16x16x32_bf16(a2, bv0, acc[2][0], 0, 0, 0); \
        acc[2][1] = __builtin_amdgcn_mfma_f32_16x16x32_bf16(a2, bv1, acc[2][1], 0, 0, 0); \
        acc[2][2] = __builtin_amdgcn_mfma_f32_16x16x32_bf16(a2, bv2, acc[2][2], 0, 0, 0); \
        acc[2][3] = __builtin_amdgcn_mfma_f32_16x16x32_bf16(a2, bv3, acc[2][3], 0, 0, 0); \
        acc[3][0] = __builtin_amdgcn_mfma_f32_16x16x32_bf16(a3, bv0, acc[3][0], 0, 0, 0); \
        acc[3][1] = __builtin_amdgcn_mfma_f32_16x16x32_bf16(a3, bv1, acc[3][1], 0, 0, 0); \
        acc[3][2] = __builtin_amdgcn_mfma_f32_16x16x32_bf16(a3, bv2, acc[3][2], 0, 0, 0); \
        acc[3][3] = __builtin_amdgcn_mfma_f32_16x16x32_bf16(a3, bv3, acc[3][3], 0, 0, 0); \
        __builtin_amdgcn_s_setprio(0);                                          \
        __builtin_amdgcn_s_barrier();                                           \
        __builtin_amdgcn_sched_barrier(0);                                      \
    }

#define PIPE_PHASE2(SLOT, DO_STAGE, STAGE_B_BASE, STAGE_B_LDS)                  \
    {                                                                           \
        const unsigned short* pa = &sA[SLOT][0];                                \
        bf16x8 a0 = *(bf16x8*)&pa[aoff0 + 2048];                                \
        bf16x8 a1 = *(bf16x8*)&pa[aoff0 + 2560];                                \
        bf16x8 a2 = *(bf16x8*)&pa[aoff0 + 3072];                                \
        bf16x8 a3 = *(bf16x8*)&pa[aoff0 + 3584];                                \
        if (DO_STAGE) stageT(STAGE_B_BASE, strideB, STAGE_B_LDS);               \
        __builtin_amdgcn_s_barrier();                                           \
        asm volatile("s_waitcnt lgkmcnt(0)" ::: "memory");                      \
        __builtin_amdgcn_sched_barrier(0);                                      \
        __builtin_amdgcn_s_setprio(1);                                          \
        acc[4][0] = __builtin_amdgcn_mfma_f32_16x16x32_bf16(a0, bv0, acc[4][0], 0, 0, 0); \
        acc[4][1] = __builtin_amdgcn_mfma_f32_16x16x32_bf16(a0, bv1, acc[4][1], 0, 0, 0); \
        acc[4][2] = __builtin_amdgcn_mfma_f32_16x16x32_bf16(a0, bv2, acc[4][2], 0, 0, 0); \
        acc[4][3] = __builtin_amdgcn_mfma_f32_16x16x32_bf16(a0, bv3, acc[4][3], 0, 0, 0); \
        acc[5][0] = __builtin_amdgcn_mfma_f32_16x16x32_bf16(a1, bv0, acc[5][0], 0, 0, 0); \
        acc[5][1] = __builtin_amdgcn_mfma_f32_16x16x32_bf16(a1, bv1, acc[5][1], 0, 0, 0); \
        acc[5][2] = __builtin_amdgcn_mfma_f32_16x16x32_bf16(a1, bv2, acc[5][2], 0, 0, 0); \
        acc[5][3] = __builtin_amdgcn_mfma_f32_16x16x32_bf16(a1, bv3, acc[5][3], 0, 0, 0); \
        acc[6][0] = __builtin_amdgcn_mfma_f32_16x16x32_bf16(a2, bv0, acc[6][0], 0, 0, 0); \
        acc[6][1] = __builtin_amdgcn_mfma_f32_16x16x32_bf16(a2, bv1, acc[6][1], 0, 0, 0); \
        acc[6][2] = __builtin_amdgcn_mfma_f32_16x16x32_bf16(a2, bv2, acc[6][2], 0, 0, 0); \
        acc[6][3] = __builtin_amdgcn_mfma_f32_16x16x32_bf16(a2, bv3, acc[6][3], 0, 0, 0); \
        acc[7][0] = __builtin_amdgcn_mfma_f32_16x16x32_bf16(a3, bv0, acc[7][0], 0, 0, 0); \
        acc[7][1] = __builtin_amdgcn_mfma_f32_16x16x32_bf16(a3, bv1, acc[7][1], 0, 0, 0); \
        acc[7][2] = __builtin_amdgcn_mfma_f32_16x16x32_bf16(a3, bv2, acc[7][2], 0, 0, 0); \
        acc[7][3] = __builtin_amdgcn_mfma_f32_16x16x32_bf16(a3, bv3, acc[7][3], 0, 0, 0); \
        __builtin_amdgcn_s_setprio(0);                                          \
        asm volatile("s_waitcnt vmcnt(4)" ::: "memory");                        \
        __builtin_amdgcn_s_barrier();                                           \
        __builtin_amdgcn_sched_barrier(0);                                      \
    }

// ---------------------------------------------------------------------------
// qk256: P = exp2(qb @ kb^T * sc), partial rowsums to Ppart. 512 thr.
// ---------------------------------------------------------------------------
__global__ __launch_bounds__(512, 2)
void qk256_kernel(const unsigned short* __restrict__ qb,
                  const unsigned short* __restrict__ kb,
                  unsigned short* __restrict__ P,
                  float* __restrict__ Ppart)
{
    __shared__ unsigned short sA[4][8192];
    __shared__ unsigned short sB[4][8192];

    const int bid = blockIdx.x;                    // 512 blocks
    const int lid = (bid & 7) * 64 + (bid >> 3);   // XCD-bijective swizzle
    const int b = lid >> 6;
    const int mt = (lid >> 3) & 7, nt = lid & 7;
    const int m0 = mt * 256, n0 = nt * 256;
    const size_t strideA = EMB, strideB = EMB;
    const unsigned short* Ag = qb + (size_t)b * SEQ * EMB;
    const unsigned short* Bg = kb + (size_t)b * SEQ * EMB;

    const int tid = threadIdx.x, lane = tid & 63;
    const int wid = tid >> 6, wr = wid >> 2, wn = wid & 3;
    const int r = lane & 15, g = lane >> 4;

    // per-lane staging bases (row = tid>>2, col16 = tid&3)
    const unsigned short* Asrc = Ag + (size_t)(m0 + (tid >> 2)) * strideA + (tid & 3) * 8;
    const unsigned short* Bsrc = Bg + (size_t)(n0 + (tid >> 2)) * strideB + (tid & 3) * 8;
    const int lwave = (wid << 9);                  // wid*512 elems = wave 1KB

    // frag read offsets (elems)
    const int aoff0 = (wr * 128 + r) * 32 + g * 8;
    const int boff0 = (wn * 64 + r) * 32 + g * 8;

    f32x4 acc[8][4];
#pragma unroll
    for (int i = 0; i < 8; i++)
#pragma unroll
        for (int j = 0; j < 4; j++) acc[i][j] = (f32x4)0.0f;

    const int NT = EMB / 32;                       // 32 K-tiles

    // prologue: stage tiles 0,1
    stageT(Asrc, strideA, &sA[0][lwave]);
    stageT(Bsrc, strideB, &sB[0][lwave]);
    stageT(Asrc + 32, strideA, &sA[1][lwave]);
    stageT(Bsrc + 32, strideB, &sB[1][lwave]);
    asm volatile("s_waitcnt vmcnt(4)" ::: "memory");
    __builtin_amdgcn_s_barrier();
    __builtin_amdgcn_sched_barrier(0);

    bf16x8 bv0, bv1, bv2, bv3;
    for (int T = 0; T < NT; ++T) {
        const int s = T & 3;
        const int doStage = (T + 2 < NT);
        const int s2 = (T + 2) & 3;
        PIPE_PHASE1(s, doStage, Asrc + (T + 2) * 32, &sA[s2][lwave]);
        PIPE_PHASE2(s, doStage, Bsrc + (T + 2) * 32, &sB[s2][lwave]);
    }

    // epilogue: exp2 + P write + partial rowsums
    unsigned short* Pb = P + (size_t)b * SEQ * SEQ;
    float ps[8][4];
#pragma unroll
    for (int mm = 0; mm < 8; mm++)
#pragma unroll
        for (int i = 0; i < 4; i++) ps[mm][i] = 0.f;

#pragma unroll
    for (int mm = 0; mm < 8; mm++) {
        const int ib = m0 + wr * 128 + mm * 16 + g * 4;
#pragma unroll
        for (int n = 0; n < 4; n++) {
            const int j = n0 + wn * 64 + n * 16 + r;
#pragma unroll
            for (int i = 0; i < 4; i++) {
                const float p = exp2f(acc[mm][n][i] * SC2);   // no max-sub: |S|<~6
                ps[mm][i] += p;
                Pb[(size_t)(ib + i) * SEQ + j] = f2bf(p);
            }
        }
    }
#pragma unroll
    for (int off = 1; off < 16; off <<= 1)
#pragma unroll
        for (int mm = 0; mm < 8; mm++)
#pragma unroll
            for (int i = 0; i < 4; i++)
                ps[mm][i] += __shfl_xor(ps[mm][i], off);
    if (r == 0) {
        const int slot = nt * 4 + wn;
        float* pp = Ppart + (size_t)slot * (BATCH * SEQ) + (size_t)b * SEQ;
#pragma unroll
        for (int mm = 0; mm < 8; mm++) {
            const int row = m0 + wr * 128 + mm * 16 + g * 4;
#pragma unroll
            for (int i = 0; i < 4; i++) pp[row + i] = ps[mm][i];
        }
    }
}

// ---------------------------------------------------------------------------
// rowsum finalize: rs[row] = sum over 32 slots of Ppart
// ---------------------------------------------------------------------------
__global__ __launch_bounds__(256)
void rowsum_final(const float* __restrict__ Ppart, float* __restrict__ rs)
{
    const int row = blockIdx.x * 256 + threadIdx.x;
    float s = 0.f;
#pragma unroll
    for (int slot = 0; slot < 32; slot++)
        s += Ppart[(size_t)slot * (BATCH * SEQ) + row];
    rs[row] = s;
}

// ---------------------------------------------------------------------------
// pv256: out = (P @ v) / rowsum. A=P [i][j], B=vt [d][j]. 512 thr.
// ---------------------------------------------------------------------------
__global__ __launch_bounds__(512, 2)
void pv256_kernel(const unsigned short* __restrict__ P,
                  const unsigned short* __restrict__ vt,
                  const float* __restrict__ rs,
                  float* __restrict__ out)
{
    __shared__ unsigned short sA[4][8192];
    __shared__ unsigned short sB[4][8192];

    const int bid = blockIdx.x;                    // 256 blocks
    const int lid = (bid & 7) * 32 + (bid >> 3);   // XCD-bijective swizzle
    const int b = lid >> 5;
    const int mt = (lid >> 2) & 7, nt = lid & 3;
    const int m0 = mt * 256, n0 = nt * 256;
    const size_t strideA = SEQ, strideB = SEQ;
    const unsigned short* Ag = P + (size_t)b * SEQ * SEQ;
    const unsigned short* Bg = vt + (size_t)b * EMB * SEQ;

    const int tid = threadIdx.x, lane = tid & 63;
    const int wid = tid >> 6, wr = wid >> 2, wn = wid & 3;
    const int r = lane & 15, g = lane >> 4;

    const unsigned short* Asrc = Ag + (size_t)(m0 + (tid >> 2)) * strideA + (tid & 3) * 8;
    const unsigned short* Bsrc = Bg + (size_t)(n0 + (tid >> 2)) * strideB + (tid & 3) * 8;
    const int lwave = (wid << 9);

    const int aoff0 = (wr * 128 + r) * 32 + g * 8;
    const int boff0 = (wn * 64 + r) * 32 + g * 8;

    f32x4 acc[8][4];
#pragma unroll
    for (int i = 0; i < 8; i++)
#pragma unroll
        for (int j = 0; j < 4; j++) acc[i][j] = (f32x4)0.0f;

    const int NT = SEQ / 32;                       // 64 K-tiles

    stageT(Asrc, strideA, &sA[0][lwave]);
    stageT(Bsrc, strideB, &sB[0][lwave]);
    stageT(Asrc + 32, strideA, &sA[1][lwave]);
    stageT(Bsrc + 32, strideB, &sB[1][lwave]);
    asm volatile("s_waitcnt vmcnt(4)" ::: "memory");
    __builtin_amdgcn_s_barrier();
    __builtin_amdgcn_sched_barrier(0);

    bf16x8 bv0, bv1, bv2, bv3;
    for (int T = 0; T < NT; ++T) {
        const int s = T & 3;
        const int doStage = (T + 2 < NT);
        const int s2 = (T + 2) & 3;
        PIPE_PHASE1(s, doStage, Asrc + (T + 2) * 32, &sA[s2][lwave]);
        PIPE_PHASE2(s, doStage, Bsrc + (T + 2) * 32, &sB[s2][lwave]);
    }

    float* ob = out + (size_t)b * SEQ * EMB;
    const float* rsb = rs + (size_t)b * SEQ;
#pragma unroll
    for (int mm = 0; mm < 8; mm++) {
        const int ib = m0 + wr * 128 + mm * 16 + g * 4;
#pragma unroll
        for (int i = 0; i < 4; i++) {
            const float inv = 1.0f / rsb[ib + i];
#pragma unroll
            for (int n = 0; n < 4; n++) {
                const int d = n0 + wn * 64 + n * 16 + r;
                ob[(size_t)(ib + i) * EMB + d] = acc[mm][n][i] * inv;
            }
        }
    }
}

// ---------------------------------------------------------------------------
extern "C" void kernel_launch(void* const* d_in, const int* in_sizes, int n_in,
                              void* d_out, int out_size, void* d_ws, size_t ws_size,
                              hipStream_t stream)
{
    const float* q_in = (const float*)d_in[0];
    const float* k_v  = (const float*)d_in[1];
    const float* Wq   = (const float*)d_in[2];
    const float* bq   = (const float*)d_in[3];
    const float* Wk   = (const float*)d_in[4];
    const float* bk   = (const float*)d_in[5];
    const float* Wv   = (const float*)d_in[6];
    const float* bv   = (const float*)d_in[7];
    float* out = (float*)d_out;

    // workspace layout (bytes):
    //   qbin  bf16 [8][2048][1024] @ 0      -- dead after proj_q
    //   kvbin bf16 [8][2048][1024] @ 32 MB  -- dead after proj_kv
    //   P     bf16 [8][2048][2048] @ 0      -- aliases qbin+kvbin
    //   qb    @ 64 MB ; kb @ 96 MB ; vt @ 128 MB ; Wt @ 160 MB
    //   Ppart f32 [32][16384] @ 166 MB ; rs @ 168 MB
    char* ws = (char*)d_ws;
    unsigned short* qbin = (unsigned short*)(ws);
    unsigned short* kvbin= (unsigned short*)(ws + (size_t)33554432);
    unsigned short* P    = (unsigned short*)(ws);
    unsigned short* qb   = (unsigned short*)(ws + (size_t)67108864);
    unsigned short* kb   = (unsigned short*)(ws + (size_t)100663296);
    unsigned short* vt   = (unsigned short*)(ws + (size_t)134217728);
    unsigned short* Wt   = (unsigned short*)(ws + (size_t)167772160);
    float*          Ppart= (float*)(ws + (size_t)174063616);
    float*          rs   = (float*)(ws + (size_t)176160768);

    convert_in<<<4096, 256, 0, stream>>>(q_in, k_v, qbin, kvbin);
    convert_w<<<dim3(256, 3), 256, 0, stream>>>(Wq, Wk, Wv, Wt);
    proj_q_kernel<<<1024, 256, 0, stream>>>(qbin, Wt, bq, qb);
    proj_kv_kernel<<<1024, 256, 0, stream>>>(kvbin, Wt + (size_t)EMB * EMB,
                                             Wt + (size_t)2 * EMB * EMB, bk, bv, kb, vt);
    qk256_kernel<<<512, 512, 0, stream>>>(qb, kb, P, Ppart);
    rowsum_final<<<64, 256, 0, stream>>>(Ppart, rs);
    pv256_kernel<<<256, 512, 0, stream>>>(P, vt, rs, out);
}

// Round 5
// 323.629 us; speedup vs baseline: 1.1357x; 1.0189x over previous
//
#include <hip/hip_runtime.h>
#include <hip/hip_bf16.h>

// CrossAttention: q = q_in@Wq+bq; k = k_v@Wk+bk; v = k_v@Wv+bv
// S = q@k^T * EMBED^-0.5 ; P = softmax(S) ; out = P@v
// B=8, I=J=2048, D=1024. All f32 in/out; internal compute bf16 MFMA.

#define BATCH 8
#define SEQ   2048
#define EMB   1024
#define SC2   0.045084222f         // EMB^-0.5 * log2(e)

typedef __attribute__((ext_vector_type(8))) short bf16x8;
typedef __attribute__((ext_vector_type(4))) float f32x4;
typedef __attribute__((ext_vector_type(4))) unsigned short u16x4;
typedef __attribute__((ext_vector_type(8))) unsigned short u16x8;
typedef __attribute__((ext_vector_type(4))) float fl4;

__device__ __forceinline__ unsigned short f2bf(float f) {
    unsigned u = __builtin_bit_cast(unsigned, f);
    unsigned r = u + 0x7fffu + ((u >> 16) & 1u);   // RNE
    return (unsigned short)(r >> 16);
}
__device__ __forceinline__ float bf2f(unsigned short s) {
    return __builtin_bit_cast(float, ((unsigned)s) << 16);
}
__device__ __forceinline__ void gload16(const unsigned short* g, unsigned short* l) {
    __builtin_amdgcn_global_load_lds(
        (const __attribute__((address_space(1))) void*)g,
        (__attribute__((address_space(3))) void*)l, 16, 0, 0);
}

// ---------------------------------------------------------------------------
// convert f32 inputs -> bf16
// ---------------------------------------------------------------------------
__global__ __launch_bounds__(256)
void convert_in(const float* __restrict__ q_in, const float* __restrict__ k_v,
                unsigned short* __restrict__ qbin, unsigned short* __restrict__ kvbin)
{
    const size_t N = (size_t)BATCH * SEQ * EMB;
    size_t idx = ((size_t)blockIdx.x * 256 + threadIdx.x) * 8;
    const size_t stride = (size_t)gridDim.x * 256 * 8;
    for (; idx < N; idx += stride) {
        fl4 a0 = *(const fl4*)&q_in[idx];
        fl4 a1 = *(const fl4*)&q_in[idx + 4];
        fl4 b0 = *(const fl4*)&k_v[idx];
        fl4 b1 = *(const fl4*)&k_v[idx + 4];
        u16x8 ua, ub;
#pragma unroll
        for (int i = 0; i < 4; i++) {
            ua[i] = f2bf(a0[i]); ua[i + 4] = f2bf(a1[i]);
            ub[i] = f2bf(b0[i]); ub[i + 4] = f2bf(b1[i]);
        }
        *(u16x8*)&qbin[idx] = ua;
        *(u16x8*)&kvbin[idx] = ub;
    }
}

// ---------------------------------------------------------------------------
// convert + transpose W [k][n] f32 -> Wt [n][k] bf16 (Wq,Wk,Wv concatenated)
// ---------------------------------------------------------------------------
__global__ __launch_bounds__(256)
void convert_w(const float* __restrict__ Wq, const float* __restrict__ Wk,
               const float* __restrict__ Wv, unsigned short* __restrict__ Wt)
{
    const int wsel = blockIdx.y;
    const float* W = (wsel == 0) ? Wq : (wsel == 1) ? Wk : Wv;
    unsigned short* O = Wt + (size_t)wsel * EMB * EMB;
    const int k0 = (blockIdx.x >> 4) * 64;
    const int n0 = (blockIdx.x & 15) * 64;
    __shared__ unsigned short l[64 * 65];
    const int tid = threadIdx.x;
#pragma unroll
    for (int it = 0; it < 16; it++) {
        const int lin = it * 256 + tid;
        const int k = lin >> 6, n = lin & 63;
        l[n * 65 + k] = f2bf(W[(size_t)(k0 + k) * EMB + n0 + n]);
    }
    __syncthreads();
#pragma unroll
    for (int it = 0; it < 16; it++) {
        const int lin = it * 256 + tid;
        const int n = lin >> 6, k = lin & 63;
        O[(size_t)(n0 + n) * EMB + k0 + k] = l[n * 65 + k];
    }
}

// ---------------------------------------------------------------------------
// Shared deep-pipelined 256x256 GEMM core (BK=32, 8 waves, 4-slot LDS ring).
// LDS tile [256][32] bf16 (64 B rows): aggregate-conflict-free ds_read_b128.
// Schedule (proven r4): tile T staged at phases 2T-3/2T-2, first read 2T+1;
// vmcnt(4)+barrier at end of each tile's phase 2.
// Wave wid: wr=wid>>2 (A-side 128-half), wn=wid&3 (B-side 64-quarter).
// acc[mm][n]: A-row = mm*16+g*4+reg, B-row = n*16+r.
// ---------------------------------------------------------------------------
__device__ __forceinline__ void stageT(const unsigned short* lanebase, size_t rstride,
                                       unsigned short* lwave) {
#pragma unroll
    for (int i = 0; i < 2; i++)
        gload16(lanebase + (size_t)(i * 128) * rstride, lwave + i * 4096);
}

#define PIPE_PHASE1(SLOT, DO_STAGE, STAGE_A_BASE, STAGE_A_LDS)                  \
    {                                                                           \
        const unsigned short* pa = &sA[SLOT][0];                                \
        const unsigned short* pb = &sB[SLOT][0];                                \
        bf16x8 a0 = *(bf16x8*)&pa[aoff0];                                       \
        bf16x8 a1 = *(bf16x8*)&pa[aoff0 + 512];                                 \
        bf16x8 a2 = *(bf16x8*)&pa[aoff0 + 1024];                                \
        bf16x8 a3 = *(bf16x8*)&pa[aoff0 + 1536];                                \
        bv0 = *(bf16x8*)&pb[boff0];                                             \
        bv1 = *(bf16x8*)&pb[boff0 + 512];                                       \
        bv2 = *(bf16x8*)&pb[boff0 + 1024];                                      \
        bv3 = *(bf16x8*)&pb[boff0 + 1536];                                      \
        if (DO_STAGE) stageT(STAGE_A_BASE, strideA, STAGE_A_LDS);               \
        __builtin_amdgcn_s_barrier();                                           \
        asm volatile("s_waitcnt lgkmcnt(0)" ::: "memory");                      \
        __builtin_amdgcn_sched_barrier(0);                                      \
        __builtin_amdgcn_s_setprio(1);                                          \
        acc[0][0] = __builtin_amdgcn_mfma_f32_16x16x32_bf16(a0, bv0, acc[0][0], 0, 0, 0); \
        acc[0][1] = __builtin_amdgcn_mfma_f32_16x16x32_bf16(a0, bv1, acc[0][1], 0, 0, 0); \
        acc[0][2] = __builtin_amdgcn_mfma_f32_16x16x32_bf16(a0, bv2, acc[0][2], 0, 0, 0); \
        acc[0][3] = __builtin_amdgcn_mfma_f32_16x16x32_bf16(a0, bv3, acc[0][3], 0, 0, 0); \
        acc[1][0] = __builtin_amdgcn_mfma_f32_16x16x32_bf16(a1, bv0, acc[1][0], 0, 0, 0); \
        acc[1][1] = __builtin_amdgcn_mfma_f32_16x16x32_bf16(a1, bv1, acc[1][1], 0, 0, 0); \
        acc[1][2] = __builtin_amdgcn_mfma_f32_16x16x32_bf16(a1, bv2, acc[1][2], 0, 0, 0); \
        acc[1][3] = __builtin_amdgcn_mfma_f32_16x16x32_bf16(a1, bv3, acc[1][3], 0, 0, 0); \
        acc[2][0] = __builtin_amdgcn_mfma_f32_16x16x32_bf16(a2, bv0, acc[2][0], 0, 0, 0); \
        acc[2][1] = __builtin_amdgcn_mfma_f32_16x16x32_bf16(a2, bv1, acc[2][1], 0, 0, 0); \
        acc[2][2] = __builtin_amdgcn_mfma_f32_16x16x32_bf16(a2, bv2, acc[2][2], 0, 0, 0); \
        acc[2][3] = __builtin_amdgcn_mfma_f32_16x16x32_bf16(a2, bv3, acc[2][3], 0, 0, 0); \
        acc[3][0] = __builtin_amdgcn_mfma_f32_16x16x32_bf16(a3, bv0, acc[3][0], 0, 0, 0); \
        acc[3][1] = __builtin_amdgcn_mfma_f32_16x16x32_bf16(a3, bv1, acc[3][1], 0, 0, 0); \
        acc[3][2] = __builtin_amdgcn_mfma_f32_16x16x32_bf16(a3, bv2, acc[3][2], 0, 0, 0); \
        acc[3][3] = __builtin_amdgcn_mfma_f32_16x16x32_bf16(a3, bv3, acc[3][3], 0, 0, 0); \
        __builtin_amdgcn_s_setprio(0);                                          \
        __builtin_amdgcn_s_barrier();                                           \
        __builtin_amdgcn_sched_barrier(0);                                      \
    }

#define PIPE_PHASE2(SLOT, DO_STAGE, STAGE_B_BASE, STAGE_B_LDS)                  \
    {                                                                           \
        const unsigned short* pa = &sA[SLOT][0];                                \
        bf16x8 a0 = *(bf16x8*)&pa[aoff0 + 2048];                                \
        bf16x8 a1 = *(bf16x8*)&pa[aoff0 + 2560];                                \
        bf16x8 a2 = *(bf16x8*)&pa[aoff0 + 3072];                                \
        bf16x8 a3 = *(bf16x8*)&pa[aoff0 + 3584];                                \
        if (DO_STAGE) stageT(STAGE_B_BASE, strideB, STAGE_B_LDS);               \
        __builtin_amdgcn_s_barrier();                                           \
        asm volatile("s_waitcnt lgkmcnt(0)" ::: "memory");                      \
        __builtin_amdgcn_sched_barrier(0);                                      \
        __builtin_amdgcn_s_setprio(1);                                          \
        acc[4][0] = __builtin_amdgcn_mfma_f32_16x16x32_bf16(a0, bv0, acc[4][0], 0, 0, 0); \
        acc[4][1] = __builtin_amdgcn_mfma_f32_16x16x32_bf16(a0, bv1, acc[4][1], 0, 0, 0); \
        acc[4][2] = __builtin_amdgcn_mfma_f32_16x16x32_bf16(a0, bv2, acc[4][2], 0, 0, 0); \
        acc[4][3] = __builtin_amdgcn_mfma_f32_16x16x32_bf16(a0, bv3, acc[4][3], 0, 0, 0); \
        acc[5][0] = __builtin_amdgcn_mfma_f32_16x16x32_bf16(a1, bv0, acc[5][0], 0, 0, 0); \
        acc[5][1] = __builtin_amdgcn_mfma_f32_16x16x32_bf16(a1, bv1, acc[5][1], 0, 0, 0); \
        acc[5][2] = __builtin_amdgcn_mfma_f32_16x16x32_bf16(a1, bv2, acc[5][2], 0, 0, 0); \
        acc[5][3] = __builtin_amdgcn_mfma_f32_16x16x32_bf16(a1, bv3, acc[5][3], 0, 0, 0); \
        acc[6][0] = __builtin_amdgcn_mfma_f32_16x16x32_bf16(a2, bv0, acc[6][0], 0, 0, 0); \
        acc[6][1] = __builtin_amdgcn_mfma_f32_16x16x32_bf16(a2, bv1, acc[6][1], 0, 0, 0); \
        acc[6][2] = __builtin_amdgcn_mfma_f32_16x16x32_bf16(a2, bv2, acc[6][2], 0, 0, 0); \
        acc[6][3] = __builtin_amdgcn_mfma_f32_16x16x32_bf16(a2, bv3, acc[6][3], 0, 0, 0); \
        acc[7][0] = __builtin_amdgcn_mfma_f32_16x16x32_bf16(a3, bv0, acc[7][0], 0, 0, 0); \
        acc[7][1] = __builtin_amdgcn_mfma_f32_16x16x32_bf16(a3, bv1, acc[7][1], 0, 0, 0); \
        acc[7][2] = __builtin_amdgcn_mfma_f32_16x16x32_bf16(a3, bv2, acc[7][2], 0, 0, 0); \
        acc[7][3] = __builtin_amdgcn_mfma_f32_16x16x32_bf16(a3, bv3, acc[7][3], 0, 0, 0); \
        __builtin_amdgcn_s_setprio(0);                                          \
        asm volatile("s_waitcnt vmcnt(4)" ::: "memory");                        \
        __builtin_amdgcn_s_barrier();                                           \
        __builtin_amdgcn_sched_barrier(0);                                      \
    }

__device__ __forceinline__ void pipe_gemm(
    const unsigned short* __restrict__ Asrc,
    const unsigned short* __restrict__ Bsrc,
    const size_t strideA, const size_t strideB, const int NT,
    unsigned short (*sA)[8192], unsigned short (*sB)[8192],
    const int lwave, const int aoff0, const int boff0,
    f32x4 acc[8][4])
{
    stageT(Asrc, strideA, &sA[0][lwave]);
    stageT(Bsrc, strideB, &sB[0][lwave]);
    stageT(Asrc + 32, strideA, &sA[1][lwave]);
    stageT(Bsrc + 32, strideB, &sB[1][lwave]);
    asm volatile("s_waitcnt vmcnt(4)" ::: "memory");
    __builtin_amdgcn_s_barrier();
    __builtin_amdgcn_sched_barrier(0);

    bf16x8 bv0, bv1, bv2, bv3;
    for (int T = 0; T < NT; ++T) {
        const int s = T & 3;
        const int doStage = (T + 2 < NT);
        const int s2 = (T + 2) & 3;
        PIPE_PHASE1(s, doStage, Asrc + (T + 2) * 32, &sA[s2][lwave]);
        PIPE_PHASE2(s, doStage, Bsrc + (T + 2) * 32, &sB[s2][lwave]);
    }
}

#define PIPE_PREAMBLE                                                     \
    __shared__ unsigned short sA[4][8192];                                \
    __shared__ unsigned short sB[4][8192];                                \
    const int tid = threadIdx.x, lane = tid & 63;                         \
    const int wid = tid >> 6, wr = wid >> 2, wn = wid & 3;                \
    const int r = lane & 15, g = lane >> 4;                               \
    const int lwave = (wid << 9);                                         \
    const int aoff0 = (wr * 128 + r) * 32 + g * 8;                        \
    const int boff0 = (wn * 64 + r) * 32 + g * 8;                         \
    f32x4 acc[8][4];                                                      \
    _Pragma("unroll") for (int i_ = 0; i_ < 8; i_++)                      \
    _Pragma("unroll") for (int j_ = 0; j_ < 4; j_++) acc[i_][j_] = (f32x4)0.0f;

// ---------------------------------------------------------------------------
// proj_q (swapped): A = WqT rows (dout), B = qbin rows (i).
// qb[i][d] = f2bf(acc + bq[d]); reg-dim = d -> u16x4 stores.
// ---------------------------------------------------------------------------
__global__ __launch_bounds__(512, 1)
void proj_q256(const unsigned short* __restrict__ Wqt,
               const unsigned short* __restrict__ X,
               const float* __restrict__ bias,
               unsigned short* __restrict__ qb)
{
    PIPE_PREAMBLE
    const int bid = blockIdx.x;                 // 256 blocks
    const int lid = (bid & 7) * 32 + (bid >> 3);
    const int dt = lid & 3, it = lid >> 2;
    const int d0 = dt * 256, i0 = it * 256;
    const size_t strideA = EMB, strideB = EMB;
    const unsigned short* Asrc = Wqt + (size_t)(d0 + (tid >> 2)) * EMB + (tid & 3) * 8;
    const unsigned short* Bsrc = X + (size_t)(i0 + (tid >> 2)) * EMB + (tid & 3) * 8;

    pipe_gemm(Asrc, Bsrc, strideA, strideB, EMB / 32, sA, sB, lwave, aoff0, boff0, acc);

#pragma unroll
    for (int mm = 0; mm < 8; mm++) {
        const int dbase = d0 + wr * 128 + mm * 16 + g * 4;
        const fl4 b4 = *(const fl4*)&bias[dbase];
#pragma unroll
        for (int n = 0; n < 4; n++) {
            const int i = i0 + wn * 64 + n * 16 + r;
            u16x4 u;
#pragma unroll
            for (int c = 0; c < 4; c++) u[c] = f2bf(acc[mm][n][c] + b4[c]);
            *(u16x4*)&qb[(size_t)i * EMB + dbase] = u;
        }
    }
}

// ---------------------------------------------------------------------------
// proj_kv (non-swapped): A = kvbin rows (i), B = WkvT rows (n over 2048: k|v).
// n<1024 -> kb[i][n] (scalar); n>=1024 -> vt[b][n-1024][j=i] (u16x4 along i).
// ---------------------------------------------------------------------------
__global__ __launch_bounds__(512, 1)
void proj_kv256(const unsigned short* __restrict__ X,
                const unsigned short* __restrict__ Wkvt,
                const float* __restrict__ bk, const float* __restrict__ bv,
                unsigned short* __restrict__ kb, unsigned short* __restrict__ vt)
{
    PIPE_PREAMBLE
    const int bid = blockIdx.x;                 // 512 blocks
    const int lid = (bid & 7) * 64 + (bid >> 3);
    const int nt = lid & 7, mt = lid >> 3;
    const int m0 = mt * 256, n0 = nt * 256;
    const size_t strideA = EMB, strideB = EMB;
    const unsigned short* Asrc = X + (size_t)(m0 + (tid >> 2)) * EMB + (tid & 3) * 8;
    const unsigned short* Bsrc = Wkvt + (size_t)(n0 + (tid >> 2)) * EMB + (tid & 3) * 8;

    pipe_gemm(Asrc, Bsrc, strideA, strideB, EMB / 32, sA, sB, lwave, aoff0, boff0, acc);

    const int b = m0 >> 11;                     // batch of this 256-row i-tile
    const int j0l = m0 & 2047;
    if (n0 < 1024) {                            // k-output (block-uniform)
#pragma unroll
        for (int mm = 0; mm < 8; mm++) {
            const int ibase = m0 + wr * 128 + mm * 16 + g * 4;
#pragma unroll
            for (int n = 0; n < 4; n++) {
                const int col = n0 + wn * 64 + n * 16 + r;
                const float bb = bk[col];
#pragma unroll
                for (int c = 0; c < 4; c++)
                    kb[(size_t)(ibase + c) * EMB + col] = f2bf(acc[mm][n][c] + bb);
            }
        }
    } else {                                    // v-output, transposed
#pragma unroll
        for (int mm = 0; mm < 8; mm++) {
            const int jbase = j0l + wr * 128 + mm * 16 + g * 4;
#pragma unroll
            for (int n = 0; n < 4; n++) {
                const int d = n0 - 1024 + wn * 64 + n * 16 + r;
                const float bb = bv[d];
                u16x4 u;
#pragma unroll
                for (int c = 0; c < 4; c++) u[c] = f2bf(acc[mm][n][c] + bb);
                *(u16x4*)&vt[((size_t)b * EMB + d) * SEQ + jbase] = u;
            }
        }
    }
}

// ---------------------------------------------------------------------------
// qk (swapped): A = kb rows (j), B = qb rows (i). P[i][j] = exp2(S*sc),
// reg-dim = j -> u16x4 stores. Partial rowsums (16 slots) to Ppart.
// ---------------------------------------------------------------------------
__global__ __launch_bounds__(512, 1)
void qk256_kernel(const unsigned short* __restrict__ qb,
                  const unsigned short* __restrict__ kb,
                  unsigned short* __restrict__ P,
                  float* __restrict__ Ppart)
{
    PIPE_PREAMBLE
    const int bid = blockIdx.x;                 // 512 blocks
    const int lid = (bid & 7) * 64 + (bid >> 3);
    const int b = lid >> 6, jt = (lid >> 3) & 7, it = lid & 7;
    const int j0 = jt * 256, i0 = it * 256;
    const size_t strideA = EMB, strideB = EMB;
    const unsigned short* Ag = kb + (size_t)b * SEQ * EMB;
    const unsigned short* Bg = qb + (size_t)b * SEQ * EMB;
    const unsigned short* Asrc = Ag + (size_t)(j0 + (tid >> 2)) * EMB + (tid & 3) * 8;
    const unsigned short* Bsrc = Bg + (size_t)(i0 + (tid >> 2)) * EMB + (tid & 3) * 8;

    pipe_gemm(Asrc, Bsrc, strideA, strideB, EMB / 32, sA, sB, lwave, aoff0, boff0, acc);

    unsigned short* Pb = P + (size_t)b * SEQ * SEQ;
    float ps[4] = {0.f, 0.f, 0.f, 0.f};
#pragma unroll
    for (int mm = 0; mm < 8; mm++) {
        const int jbase = j0 + wr * 128 + mm * 16 + g * 4;
#pragma unroll
        for (int n = 0; n < 4; n++) {
            const int i = i0 + wn * 64 + n * 16 + r;
            u16x4 u;
#pragma unroll
            for (int c = 0; c < 4; c++) {
                const float p = exp2f(acc[mm][n][c] * SC2);   // no max-sub: |S|<~6
                ps[n] += p;
                u[c] = f2bf(p);
            }
            *(u16x4*)&Pb[(size_t)i * SEQ + jbase] = u;
        }
    }
    // reduce over g (j-direction): lanes xor 16, 32
#pragma unroll
    for (int n = 0; n < 4; n++) {
        ps[n] += __shfl_xor(ps[n], 16);
        ps[n] += __shfl_xor(ps[n], 32);
    }
    if (g == 0) {
        const int slot = jt * 2 + wr;
        float* pp = Ppart + (size_t)slot * (BATCH * SEQ) + (size_t)b * SEQ;
#pragma unroll
        for (int n = 0; n < 4; n++)
            pp[i0 + wn * 64 + n * 16 + r] = ps[n];
    }
}

// ---------------------------------------------------------------------------
// rowsum finalize: rs[row] = sum over 16 slots
// ---------------------------------------------------------------------------
__global__ __launch_bounds__(256)
void rowsum_final(const float* __restrict__ Ppart, float* __restrict__ rs)
{
    const int row = blockIdx.x * 256 + threadIdx.x;
    float s = 0.f;
#pragma unroll
    for (int slot = 0; slot < 16; slot++)
        s += Ppart[(size_t)slot * (BATCH * SEQ) + row];
    rs[row] = s;
}

// ---------------------------------------------------------------------------
// pv (swapped): A = vt rows (d), B = P rows (i). out[i][d] = acc/rs[i],
// reg-dim = d -> fl4 stores.
// ---------------------------------------------------------------------------
__global__ __launch_bounds__(512, 1)
void pv256_kernel(const unsigned short* __restrict__ P,
                  const unsigned short* __restrict__ vt,
                  const float* __restrict__ rs,
                  float* __restrict__ out)
{
    PIPE_PREAMBLE
    const int bid = blockIdx.x;                 // 256 blocks
    const int lid = (bid & 7) * 32 + (bid >> 3);
    const int b = lid >> 5, it = (lid >> 2) & 7, dt = lid & 3;
    const int d0 = dt * 256, i0 = it * 256;
    const size_t strideA = SEQ, strideB = SEQ;
    const unsigned short* Ag = vt + (size_t)b * EMB * SEQ;
    const unsigned short* Bg = P + (size_t)b * SEQ * SEQ;
    const unsigned short* Asrc = Ag + (size_t)(d0 + (tid >> 2)) * SEQ + (tid & 3) * 8;
    const unsigned short* Bsrc = Bg + (size_t)(i0 + (tid >> 2)) * SEQ + (tid & 3) * 8;

    pipe_gemm(Asrc, Bsrc, strideA, strideB, SEQ / 32, sA, sB, lwave, aoff0, boff0, acc);

    float* ob = out + (size_t)b * SEQ * EMB;
    const float* rsb = rs + (size_t)b * SEQ;
    float inv[4];
#pragma unroll
    for (int n = 0; n < 4; n++)
        inv[n] = 1.0f / rsb[i0 + wn * 64 + n * 16 + r];
#pragma unroll
    for (int mm = 0; mm < 8; mm++) {
        const int dbase = d0 + wr * 128 + mm * 16 + g * 4;
#pragma unroll
        for (int n = 0; n < 4; n++) {
            const int i = i0 + wn * 64 + n * 16 + r;
            fl4 o;
#pragma unroll
            for (int c = 0; c < 4; c++) o[c] = acc[mm][n][c] * inv[n];
            *(fl4*)&ob[(size_t)i * EMB + dbase] = o;
        }
    }
}

// ---------------------------------------------------------------------------
extern "C" void kernel_launch(void* const* d_in, const int* in_sizes, int n_in,
                              void* d_out, int out_size, void* d_ws, size_t ws_size,
                              hipStream_t stream)
{
    const float* q_in = (const float*)d_in[0];
    const float* k_v  = (const float*)d_in[1];
    const float* Wq   = (const float*)d_in[2];
    const float* bq   = (const float*)d_in[3];
    const float* Wk   = (const float*)d_in[4];
    const float* bk   = (const float*)d_in[5];
    const float* Wv   = (const float*)d_in[6];
    const float* bv   = (const float*)d_in[7];
    float* out = (float*)d_out;

    // workspace layout (bytes):
    //   qbin  bf16 [8][2048][1024] @ 0      -- dead after proj_q
    //   kvbin bf16 [8][2048][1024] @ 32 MB  -- dead after proj_kv
    //   P     bf16 [8][2048][2048] @ 0      -- aliases qbin+kvbin
    //   qb @ 64 MB ; kb @ 96 MB ; vt @ 128 MB ; Wt (WqT|WkT|WvT) @ 160 MB
    //   Ppart f32 [16][16384] @ 166 MB ; rs @ 167 MB
    char* ws = (char*)d_ws;
    unsigned short* qbin = (unsigned short*)(ws);
    unsigned short* kvbin= (unsigned short*)(ws + (size_t)33554432);
    unsigned short* P    = (unsigned short*)(ws);
    unsigned short* qb   = (unsigned short*)(ws + (size_t)67108864);
    unsigned short* kb   = (unsigned short*)(ws + (size_t)100663296);
    unsigned short* vt   = (unsigned short*)(ws + (size_t)134217728);
    unsigned short* Wt   = (unsigned short*)(ws + (size_t)167772160);
    float*          Ppart= (float*)(ws + (size_t)174063616);
    float*          rs   = (float*)(ws + (size_t)175112192);

    convert_in<<<4096, 256, 0, stream>>>(q_in, k_v, qbin, kvbin);
    convert_w<<<dim3(256, 3), 256, 0, stream>>>(Wq, Wk, Wv, Wt);
    proj_q256<<<256, 512, 0, stream>>>(Wt, qbin, bq, qb);
    proj_kv256<<<512, 512, 0, stream>>>(kvbin, Wt + (size_t)EMB * EMB, bk, bv, kb, vt);
    qk256_kernel<<<512, 512, 0, stream>>>(qb, kb, P, Ppart);
    rowsum_final<<<64, 256, 0, stream>>>(Ppart, rs);
    pv256_kernel<<<256, 512, 0, stream>>>(P, vt, rs, out);
}

// Round 6
// 315.151 us; speedup vs baseline: 1.1662x; 1.0269x over previous
//
#include <hip/hip_runtime.h>
#include <hip/hip_bf16.h>

// CrossAttention: q = q_in@Wq+bq; k = k_v@Wk+bk; v = k_v@Wv+bv
// S = q@k^T * EMBED^-0.5 ; P = softmax(S) ; out = P@v
// B=8, I=J=2048, D=1024. All f32 in/out; internal compute bf16 MFMA.

#define BATCH 8
#define SEQ   2048
#define EMB   1024
#define SC2   0.045084222f         // EMB^-0.5 * log2(e)

typedef __attribute__((ext_vector_type(8))) short bf16x8;
typedef __attribute__((ext_vector_type(4))) float f32x4;
typedef __attribute__((ext_vector_type(4))) unsigned short u16x4;
typedef __attribute__((ext_vector_type(8))) unsigned short u16x8;
typedef __attribute__((ext_vector_type(4))) float fl4;

__device__ __forceinline__ unsigned short f2bf(float f) {
    unsigned u = __builtin_bit_cast(unsigned, f);
    unsigned r = u + 0x7fffu + ((u >> 16) & 1u);   // RNE
    return (unsigned short)(r >> 16);
}
__device__ __forceinline__ float bf2f(unsigned short s) {
    return __builtin_bit_cast(float, ((unsigned)s) << 16);
}
__device__ __forceinline__ void gload16(const unsigned short* g, unsigned short* l) {
    __builtin_amdgcn_global_load_lds(
        (const __attribute__((address_space(1))) void*)g,
        (__attribute__((address_space(3))) void*)l, 16, 0, 0);
}

// ---------------------------------------------------------------------------
// convert f32 inputs -> bf16
// ---------------------------------------------------------------------------
__global__ __launch_bounds__(256)
void convert_in(const float* __restrict__ q_in, const float* __restrict__ k_v,
                unsigned short* __restrict__ qbin, unsigned short* __restrict__ kvbin)
{
    const size_t N = (size_t)BATCH * SEQ * EMB;
    size_t idx = ((size_t)blockIdx.x * 256 + threadIdx.x) * 8;
    const size_t stride = (size_t)gridDim.x * 256 * 8;
    for (; idx < N; idx += stride) {
        fl4 a0 = *(const fl4*)&q_in[idx];
        fl4 a1 = *(const fl4*)&q_in[idx + 4];
        fl4 b0 = *(const fl4*)&k_v[idx];
        fl4 b1 = *(const fl4*)&k_v[idx + 4];
        u16x8 ua, ub;
#pragma unroll
        for (int i = 0; i < 4; i++) {
            ua[i] = f2bf(a0[i]); ua[i + 4] = f2bf(a1[i]);
            ub[i] = f2bf(b0[i]); ub[i + 4] = f2bf(b1[i]);
        }
        *(u16x8*)&qbin[idx] = ua;
        *(u16x8*)&kvbin[idx] = ub;
    }
}

// ---------------------------------------------------------------------------
// convert + transpose W [k][n] f32 -> Wt [n][k] bf16 (Wq,Wk,Wv concatenated)
// ---------------------------------------------------------------------------
__global__ __launch_bounds__(256)
void convert_w(const float* __restrict__ Wq, const float* __restrict__ Wk,
               const float* __restrict__ Wv, unsigned short* __restrict__ Wt)
{
    const int wsel = blockIdx.y;
    const float* W = (wsel == 0) ? Wq : (wsel == 1) ? Wk : Wv;
    unsigned short* O = Wt + (size_t)wsel * EMB * EMB;
    const int k0 = (blockIdx.x >> 4) * 64;
    const int n0 = (blockIdx.x & 15) * 64;
    __shared__ unsigned short l[64 * 65];
    const int tid = threadIdx.x;
#pragma unroll
    for (int it = 0; it < 16; it++) {
        const int lin = it * 256 + tid;
        const int k = lin >> 6, n = lin & 63;
        l[n * 65 + k] = f2bf(W[(size_t)(k0 + k) * EMB + n0 + n]);
    }
    __syncthreads();
#pragma unroll
    for (int it = 0; it < 16; it++) {
        const int lin = it * 256 + tid;
        const int n = lin >> 6, k = lin & 63;
        O[(size_t)(n0 + n) * EMB + k0 + k] = l[n * 65 + k];
    }
}

// ---------------------------------------------------------------------------
// Shared deep-pipelined 256x256 GEMM core (BK=32, 8 waves, 4-slot LDS ring).
// LDS tile [256][32] bf16 (64 B rows): aggregate-conflict-free ds_read_b128.
// Schedule (proven r4): tile T staged at phases 2T-3/2T-2, first read 2T+1;
// vmcnt(4)+barrier at end of each tile's phase 2.
// Wave wid: wr=wid>>2 (A-side 128-half), wn=wid&3 (B-side 64-quarter).
// acc[mm][n]: A-col = wr*128+mm*16+g*4+reg, B-row = wn*64+n*16+r.
// Epilogue: LDS-transpose via XOR swizzle (byte ^= (row&7)<<4) then
// coalesced row flush (32 lanes x 16B = full 512B row segment).
// ---------------------------------------------------------------------------
__device__ __forceinline__ void stageT(const unsigned short* lanebase, size_t rstride,
                                       unsigned short* lwave) {
#pragma unroll
    for (int i = 0; i < 2; i++)
        gload16(lanebase + (size_t)(i * 128) * rstride, lwave + i * 4096);
}

#define PIPE_PHASE1(SLOT, DO_STAGE, STAGE_A_BASE, STAGE_A_LDS)                  \
    {                                                                           \
        const unsigned short* pa = &sA[SLOT][0];                                \
        const unsigned short* pb = &sB[SLOT][0];                                \
        bf16x8 a0 = *(bf16x8*)&pa[aoff0];                                       \
        bf16x8 a1 = *(bf16x8*)&pa[aoff0 + 512];                                 \
        bf16x8 a2 = *(bf16x8*)&pa[aoff0 + 1024];                                \
        bf16x8 a3 = *(bf16x8*)&pa[aoff0 + 1536];                                \
        bv0 = *(bf16x8*)&pb[boff0];                                             \
        bv1 = *(bf16x8*)&pb[boff0 + 512];                                       \
        bv2 = *(bf16x8*)&pb[boff0 + 1024];                                      \
        bv3 = *(bf16x8*)&pb[boff0 + 1536];                                      \
        if (DO_STAGE) stageT(STAGE_A_BASE, strideA, STAGE_A_LDS);               \
        __builtin_amdgcn_s_barrier();                                           \
        asm volatile("s_waitcnt lgkmcnt(0)" ::: "memory");                      \
        __builtin_amdgcn_sched_barrier(0);                                      \
        __builtin_amdgcn_s_setprio(1);                                          \
        acc[0][0] = __builtin_amdgcn_mfma_f32_16x16x32_bf16(a0, bv0, acc[0][0], 0, 0, 0); \
        acc[0][1] = __builtin_amdgcn_mfma_f32_16x16x32_bf16(a0, bv1, acc[0][1], 0, 0, 0); \
        acc[0][2] = __builtin_amdgcn_mfma_f32_16x16x32_bf16(a0, bv2, acc[0][2], 0, 0, 0); \
        acc[0][3] = __builtin_amdgcn_mfma_f32_16x16x32_bf16(a0, bv3, acc[0][3], 0, 0, 0); \
        acc[1][0] = __builtin_amdgcn_mfma_f32_16x16x32_bf16(a1, bv0, acc[1][0], 0, 0, 0); \
        acc[1][1] = __builtin_amdgcn_mfma_f32_16x16x32_bf16(a1, bv1, acc[1][1], 0, 0, 0); \
        acc[1][2] = __builtin_amdgcn_mfma_f32_16x16x32_bf16(a1, bv2, acc[1][2], 0, 0, 0); \
        acc[1][3] = __builtin_amdgcn_mfma_f32_16x16x32_bf16(a1, bv3, acc[1][3], 0, 0, 0); \
        acc[2][0] = __builtin_amdgcn_mfma_f32_16x16x32_bf16(a2, bv0, acc[2][0], 0, 0, 0); \
        acc[2][1] = __builtin_amdgcn_mfma_f32_16x16x32_bf16(a2, bv1, acc[2][1], 0, 0, 0); \
        acc[2][2] = __builtin_amdgcn_mfma_f32_16x16x32_bf16(a2, bv2, acc[2][2], 0, 0, 0); \
        acc[2][3] = __builtin_amdgcn_mfma_f32_16x16x32_bf16(a2, bv3, acc[2][3], 0, 0, 0); \
        acc[3][0] = __builtin_amdgcn_mfma_f32_16x16x32_bf16(a3, bv0, acc[3][0], 0, 0, 0); \
        acc[3][1] = __builtin_amdgcn_mfma_f32_16x16x32_bf16(a3, bv1, acc[3][1], 0, 0, 0); \
        acc[3][2] = __builtin_amdgcn_mfma_f32_16x16x32_bf16(a3, bv2, acc[3][2], 0, 0, 0); \
        acc[3][3] = __builtin_amdgcn_mfma_f32_16x16x32_bf16(a3, bv3, acc[3][3], 0, 0, 0); \
        __builtin_amdgcn_s_setprio(0);                                          \
        __builtin_amdgcn_s_barrier();                                           \
        __builtin_amdgcn_sched_barrier(0);                                      \
    }

#define PIPE_PHASE2(SLOT, DO_STAGE, STAGE_B_BASE, STAGE_B_LDS)                  \
    {                                                                           \
        const unsigned short* pa = &sA[SLOT][0];                                \
        bf16x8 a0 = *(bf16x8*)&pa[aoff0 + 2048];                                \
        bf16x8 a1 = *(bf16x8*)&pa[aoff0 + 2560];                                \
        bf16x8 a2 = *(bf16x8*)&pa[aoff0 + 3072];                                \
        bf16x8 a3 = *(bf16x8*)&pa[aoff0 + 3584];                                \
        if (DO_STAGE) stageT(STAGE_B_BASE, strideB, STAGE_B_LDS);               \
        __builtin_amdgcn_s_barrier();                                           \
        asm volatile("s_waitcnt lgkmcnt(0)" ::: "memory");                      \
        __builtin_amdgcn_sched_barrier(0);                                      \
        __builtin_amdgcn_s_setprio(1);                                          \
        acc[4][0] = __builtin_amdgcn_mfma_f32_16x16x32_bf16(a0, bv0, acc[4][0], 0, 0, 0); \
        acc[4][1] = __builtin_amdgcn_mfma_f32_16x16x32_bf16(a0, bv1, acc[4][1], 0, 0, 0); \
        acc[4][2] = __builtin_amdgcn_mfma_f32_16x16x32_bf16(a0, bv2, acc[4][2], 0, 0, 0); \
        acc[4][3] = __builtin_amdgcn_mfma_f32_16x16x32_bf16(a0, bv3, acc[4][3], 0, 0, 0); \
        acc[5][0] = __builtin_amdgcn_mfma_f32_16x16x32_bf16(a1, bv0, acc[5][0], 0, 0, 0); \
        acc[5][1] = __builtin_amdgcn_mfma_f32_16x16x32_bf16(a1, bv1, acc[5][1], 0, 0, 0); \
        acc[5][2] = __builtin_amdgcn_mfma_f32_16x16x32_bf16(a1, bv2, acc[5][2], 0, 0, 0); \
        acc[5][3] = __builtin_amdgcn_mfma_f32_16x16x32_bf16(a1, bv3, acc[5][3], 0, 0, 0); \
        acc[6][0] = __builtin_amdgcn_mfma_f32_16x16x32_bf16(a2, bv0, acc[6][0], 0, 0, 0); \
        acc[6][1] = __builtin_amdgcn_mfma_f32_16x16x32_bf16(a2, bv1, acc[6][1], 0, 0, 0); \
        acc[6][2] = __builtin_amdgcn_mfma_f32_16x16x32_bf16(a2, bv2, acc[6][2], 0, 0, 0); \
        acc[6][3] = __builtin_amdgcn_mfma_f32_16x16x32_bf16(a2, bv3, acc[6][3], 0, 0, 0); \
        acc[7][0] = __builtin_amdgcn_mfma_f32_16x16x32_bf16(a3, bv0, acc[7][0], 0, 0, 0); \
        acc[7][1] = __builtin_amdgcn_mfma_f32_16x16x32_bf16(a3, bv1, acc[7][1], 0, 0, 0); \
        acc[7][2] = __builtin_amdgcn_mfma_f32_16x16x32_bf16(a3, bv2, acc[7][2], 0, 0, 0); \
        acc[7][3] = __builtin_amdgcn_mfma_f32_16x16x32_bf16(a3, bv3, acc[7][3], 0, 0, 0); \
        __builtin_amdgcn_s_setprio(0);                                          \
        asm volatile("s_waitcnt vmcnt(4)" ::: "memory");                        \
        __builtin_amdgcn_s_barrier();                                           \
        __builtin_amdgcn_sched_barrier(0);                                      \
    }

__device__ __forceinline__ void pipe_gemm(
    const unsigned short* __restrict__ Asrc,
    const unsigned short* __restrict__ Bsrc,
    const size_t strideA, const size_t strideB, const int NT,
    unsigned short (*sA)[8192], unsigned short (*sB)[8192],
    const int lwave, const int aoff0, const int boff0,
    f32x4 acc[8][4])
{
    stageT(Asrc, strideA, &sA[0][lwave]);
    stageT(Bsrc, strideB, &sB[0][lwave]);
    stageT(Asrc + 32, strideA, &sA[1][lwave]);
    stageT(Bsrc + 32, strideB, &sB[1][lwave]);
    asm volatile("s_waitcnt vmcnt(4)" ::: "memory");
    __builtin_amdgcn_s_barrier();
    __builtin_amdgcn_sched_barrier(0);

    bf16x8 bv0, bv1, bv2, bv3;
    for (int T = 0; T < NT; ++T) {
        const int s = T & 3;
        const int doStage = (T + 2 < NT);
        const int s2 = (T + 2) & 3;
        PIPE_PHASE1(s, doStage, Asrc + (T + 2) * 32, &sA[s2][lwave]);
        PIPE_PHASE2(s, doStage, Bsrc + (T + 2) * 32, &sB[s2][lwave]);
    }
}

#define PIPE_PREAMBLE                                                     \
    __shared__ unsigned short sMem[65536];  /* 128 KB */                  \
    unsigned short (*sA)[8192] = (unsigned short (*)[8192])sMem;          \
    unsigned short (*sB)[8192] = (unsigned short (*)[8192])(sMem + 32768);\
    const int tid = threadIdx.x, lane = tid & 63;                         \
    const int wid = tid >> 6, wr = wid >> 2, wn = wid & 3;                \
    const int r = lane & 15, g = lane >> 4;                               \
    const int lwave = (wid << 9);                                         \
    const int aoff0 = (wr * 128 + r) * 32 + g * 8;                        \
    const int boff0 = (wn * 64 + r) * 32 + g * 8;                         \
    f32x4 acc[8][4];                                                      \
    _Pragma("unroll") for (int i_ = 0; i_ < 8; i_++)                      \
    _Pragma("unroll") for (int j_ = 0; j_ < 4; j_++) acc[i_][j_] = (f32x4)0.0f;

// Coalesced flush of a [256 row][512 B] swizzled LDS tile to global.
// Each wave: 2 rows x 32 lanes x 16 B per iter, 16 iters.
__device__ __forceinline__ void lds_flush_bf16(const unsigned short* sP,
                                               unsigned short* gbase,
                                               size_t gstride, int tid)
{
    const int lane = tid & 63, wv = tid >> 6;
    const int rowsel = lane >> 5, jj = lane & 31;
#pragma unroll
    for (int it = 0; it < 16; ++it) {
        const int row = it * 16 + wv * 2 + rowsel;
        const int byte = row * 512 + ((jj * 16) ^ ((row & 7) << 4));
        u16x8 v = *(const u16x8*)((const char*)sP + byte);
        *(u16x8*)&gbase[(size_t)row * gstride + jj * 8] = v;
    }
}

// ---------------------------------------------------------------------------
// proj_q (swapped): A = WqT rows (d), B = qbin rows (i). qb[i][d] bf16.
// ---------------------------------------------------------------------------
__global__ __launch_bounds__(512, 1)
void proj_q256(const unsigned short* __restrict__ Wqt,
               const unsigned short* __restrict__ X,
               const float* __restrict__ bias,
               unsigned short* __restrict__ qb)
{
    PIPE_PREAMBLE
    const int bid = blockIdx.x;                 // 256 blocks
    const int lid = (bid & 7) * 32 + (bid >> 3);
    const int dt = lid & 3, it = lid >> 2;
    const int d0 = dt * 256, i0 = it * 256;
    const size_t strideA = EMB, strideB = EMB;
    const unsigned short* Asrc = Wqt + (size_t)(d0 + (tid >> 2)) * EMB + (tid & 3) * 8;
    const unsigned short* Bsrc = X + (size_t)(i0 + (tid >> 2)) * EMB + (tid & 3) * 8;

    pipe_gemm(Asrc, Bsrc, strideA, strideB, EMB / 32, sA, sB, lwave, aoff0, boff0, acc);

    // LDS transpose: row = i-local (wn,n,r), col = d-local (wr,mm,g,c)
#pragma unroll
    for (int mm = 0; mm < 8; mm++) {
        const int colb = wr * 128 + mm * 16 + g * 4;
        const fl4 b4 = *(const fl4*)&bias[d0 + colb];
#pragma unroll
        for (int n = 0; n < 4; n++) {
            const int row = wn * 64 + n * 16 + r;
            u16x4 u;
#pragma unroll
            for (int c = 0; c < 4; c++) u[c] = f2bf(acc[mm][n][c] + b4[c]);
            const int byte = row * 512 + ((colb * 2) ^ ((row & 7) << 4));
            *(u16x4*)((char*)sMem + byte) = u;
        }
    }
    __syncthreads();
    lds_flush_bf16(sMem, qb + (size_t)i0 * EMB + d0, EMB, tid);
}

// ---------------------------------------------------------------------------
// proj_kv (non-swapped): A = kvbin rows (i), B = WkvT rows (n over 2048: k|v).
// n<1024 -> kb[i][n] (coalesced scalar); n>=1024 -> vt[b][d][j] via LDS transp.
// ---------------------------------------------------------------------------
__global__ __launch_bounds__(512, 1)
void proj_kv256(const unsigned short* __restrict__ X,
                const unsigned short* __restrict__ Wkvt,
                const float* __restrict__ bk, const float* __restrict__ bv,
                unsigned short* __restrict__ kb, unsigned short* __restrict__ vt)
{
    PIPE_PREAMBLE
    const int bid = blockIdx.x;                 // 512 blocks
    const int lid = (bid & 7) * 64 + (bid >> 3);
    const int nt = lid & 7, mt = lid >> 3;
    const int m0 = mt * 256, n0 = nt * 256;
    const size_t strideA = EMB, strideB = EMB;
    const unsigned short* Asrc = X + (size_t)(m0 + (tid >> 2)) * EMB + (tid & 3) * 8;
    const unsigned short* Bsrc = Wkvt + (size_t)(n0 + (tid >> 2)) * EMB + (tid & 3) * 8;

    pipe_gemm(Asrc, Bsrc, strideA, strideB, EMB / 32, sA, sB, lwave, aoff0, boff0, acc);

    const int b = m0 >> 11;                     // batch of this 256-row i-tile
    const int j0l = m0 & 2047;
    if (n0 < 1024) {                            // k-output (block-uniform)
#pragma unroll
        for (int mm = 0; mm < 8; mm++) {
            const int ibase = m0 + wr * 128 + mm * 16 + g * 4;
#pragma unroll
            for (int n = 0; n < 4; n++) {
                const int col = n0 + wn * 64 + n * 16 + r;
                const float bb = bk[col];
#pragma unroll
                for (int c = 0; c < 4; c++)
                    kb[(size_t)(ibase + c) * EMB + col] = f2bf(acc[mm][n][c] + bb);
            }
        }
    } else {                                    // v-output: LDS transpose
        // row = d-local (wn,n,r), col = j-local (wr,mm,g,c)
#pragma unroll
        for (int mm = 0; mm < 8; mm++) {
            const int colb = wr * 128 + mm * 16 + g * 4;
#pragma unroll
            for (int n = 0; n < 4; n++) {
                const int row = wn * 64 + n * 16 + r;
                const float bb = bv[n0 - 1024 + row];
                u16x4 u;
#pragma unroll
                for (int c = 0; c < 4; c++) u[c] = f2bf(acc[mm][n][c] + bb);
                const int byte = row * 512 + ((colb * 2) ^ ((row & 7) << 4));
                *(u16x4*)((char*)sMem + byte) = u;
            }
        }
        __syncthreads();
        lds_flush_bf16(sMem, vt + ((size_t)b * EMB + (n0 - 1024)) * SEQ + j0l,
                       SEQ, tid);
    }
}

// ---------------------------------------------------------------------------
// qk (swapped): A = kb rows (j), B = qb rows (i). P[i][j] = exp2(S*sc) via
// LDS transpose; partial rowsums (16 slots) to Ppart.
// ---------------------------------------------------------------------------
__global__ __launch_bounds__(512, 1)
void qk256_kernel(const unsigned short* __restrict__ qb,
                  const unsigned short* __restrict__ kb,
                  unsigned short* __restrict__ P,
                  float* __restrict__ Ppart)
{
    PIPE_PREAMBLE
    const int bid = blockIdx.x;                 // 512 blocks
    const int lid = (bid & 7) * 64 + (bid >> 3);
    const int b = lid >> 6, jt = (lid >> 3) & 7, it = lid & 7;
    const int j0 = jt * 256, i0 = it * 256;
    const size_t strideA = EMB, strideB = EMB;
    const unsigned short* Ag = kb + (size_t)b * SEQ * EMB;
    const unsigned short* Bg = qb + (size_t)b * SEQ * EMB;
    const unsigned short* Asrc = Ag + (size_t)(j0 + (tid >> 2)) * EMB + (tid & 3) * 8;
    const unsigned short* Bsrc = Bg + (size_t)(i0 + (tid >> 2)) * EMB + (tid & 3) * 8;

    pipe_gemm(Asrc, Bsrc, strideA, strideB, EMB / 32, sA, sB, lwave, aoff0, boff0, acc);

    // LDS transpose: row = i-local (wn,n,r), col = j-local (wr,mm,g,c)
    float ps[4] = {0.f, 0.f, 0.f, 0.f};
#pragma unroll
    for (int mm = 0; mm < 8; mm++) {
        const int colb = wr * 128 + mm * 16 + g * 4;
#pragma unroll
        for (int n = 0; n < 4; n++) {
            const int row = wn * 64 + n * 16 + r;
            u16x4 u;
#pragma unroll
            for (int c = 0; c < 4; c++) {
                const float p = exp2f(acc[mm][n][c] * SC2);   // no max-sub: |S|<~6
                ps[n] += p;
                u[c] = f2bf(p);
            }
            const int byte = row * 512 + ((colb * 2) ^ ((row & 7) << 4));
            *(u16x4*)((char*)sMem + byte) = u;
        }
    }
    // partial rowsums: reduce over g (j-direction)
#pragma unroll
    for (int n = 0; n < 4; n++) {
        ps[n] += __shfl_xor(ps[n], 16);
        ps[n] += __shfl_xor(ps[n], 32);
    }
    if (g == 0) {
        const int slot = jt * 2 + wr;
        float* pp = Ppart + (size_t)slot * (BATCH * SEQ) + (size_t)b * SEQ;
#pragma unroll
        for (int n = 0; n < 4; n++)
            pp[i0 + wn * 64 + n * 16 + r] = ps[n];
    }
    __syncthreads();
    unsigned short* Pb = P + (size_t)b * SEQ * SEQ;
    lds_flush_bf16(sMem, Pb + (size_t)i0 * SEQ + j0, SEQ, tid);
}

// ---------------------------------------------------------------------------
// rowsum finalize: rs[row] = sum over 16 slots
// ---------------------------------------------------------------------------
__global__ __launch_bounds__(256)
void rowsum_final(const float* __restrict__ Ppart, float* __restrict__ rs)
{
    const int row = blockIdx.x * 256 + threadIdx.x;
    float s = 0.f;
#pragma unroll
    for (int slot = 0; slot < 16; slot++)
        s += Ppart[(size_t)slot * (BATCH * SEQ) + row];
    rs[row] = s;
}

// ---------------------------------------------------------------------------
// pv (swapped): A = vt rows (d), B = P rows (i). out[i][d] f32 via LDS
// transpose in two 128-KB chunks (d-halves selected by wr).
// ---------------------------------------------------------------------------
__global__ __launch_bounds__(512, 1)
void pv256_kernel(const unsigned short* __restrict__ P,
                  const unsigned short* __restrict__ vt,
                  const float* __restrict__ rs,
                  float* __restrict__ out)
{
    PIPE_PREAMBLE
    const int bid = blockIdx.x;                 // 256 blocks
    const int lid = (bid & 7) * 32 + (bid >> 3);
    const int b = lid >> 5, it = (lid >> 2) & 7, dt = lid & 3;
    const int d0 = dt * 256, i0 = it * 256;
    const size_t strideA = SEQ, strideB = SEQ;
    const unsigned short* Ag = vt + (size_t)b * EMB * SEQ;
    const unsigned short* Bg = P + (size_t)b * SEQ * SEQ;
    const unsigned short* Asrc = Ag + (size_t)(d0 + (tid >> 2)) * SEQ + (tid & 3) * 8;
    const unsigned short* Bsrc = Bg + (size_t)(i0 + (tid >> 2)) * SEQ + (tid & 3) * 8;

    pipe_gemm(Asrc, Bsrc, strideA, strideB, SEQ / 32, sA, sB, lwave, aoff0, boff0, acc);

    float* ob = out + (size_t)b * SEQ * EMB;
    const float* rsb = rs + (size_t)b * SEQ;
    float inv[4];
#pragma unroll
    for (int n = 0; n < 4; n++)
        inv[n] = 1.0f / rsb[i0 + wn * 64 + n * 16 + r];

    float* sF = (float*)sMem;   // [256 rows][128 f32] per chunk
#pragma unroll
    for (int h = 0; h < 2; h++) {
        if (wr == h) {
            // row = i-local (wn,n,r), col = d-local within chunk (mm,g,c)
#pragma unroll
            for (int mm = 0; mm < 8; mm++) {
                const int colb = mm * 16 + g * 4;      // 0..127
#pragma unroll
                for (int n = 0; n < 4; n++) {
                    const int row = wn * 64 + n * 16 + r;
                    fl4 o;
#pragma unroll
                    for (int c = 0; c < 4; c++) o[c] = acc[mm][n][c] * inv[n];
                    const int byte = row * 512 + ((colb * 4) ^ ((row & 7) << 4));
                    *(fl4*)((char*)sF + byte) = o;
                }
            }
        }
        __syncthreads();
        {
            const int rowsel = lane >> 5, jj = lane & 31;
#pragma unroll
            for (int itx = 0; itx < 16; ++itx) {
                const int row = itx * 16 + wid * 2 + rowsel;
                const int byte = row * 512 + ((jj * 16) ^ ((row & 7) << 4));
                fl4 v = *(const fl4*)((const char*)sF + byte);
                *(fl4*)&ob[(size_t)(i0 + row) * EMB + d0 + h * 128 + jj * 4] = v;
            }
        }
        if (h == 0) __syncthreads();
    }
}

// ---------------------------------------------------------------------------
extern "C" void kernel_launch(void* const* d_in, const int* in_sizes, int n_in,
                              void* d_out, int out_size, void* d_ws, size_t ws_size,
                              hipStream_t stream)
{
    const float* q_in = (const float*)d_in[0];
    const float* k_v  = (const float*)d_in[1];
    const float* Wq   = (const float*)d_in[2];
    const float* bq   = (const float*)d_in[3];
    const float* Wk   = (const float*)d_in[4];
    const float* bk   = (const float*)d_in[5];
    const float* Wv   = (const float*)d_in[6];
    const float* bv   = (const float*)d_in[7];
    float* out = (float*)d_out;

    // workspace layout (bytes):
    //   qbin  bf16 [8][2048][1024] @ 0      -- dead after proj_q
    //   kvbin bf16 [8][2048][1024] @ 32 MB  -- dead after proj_kv
    //   P     bf16 [8][2048][2048] @ 0      -- aliases qbin+kvbin
    //   qb @ 64 MB ; kb @ 96 MB ; vt @ 128 MB ; Wt (WqT|WkT|WvT) @ 160 MB
    //   Ppart f32 [16][16384] @ 166 MB ; rs @ 167 MB
    char* ws = (char*)d_ws;
    unsigned short* qbin = (unsigned short*)(ws);
    unsigned short* kvbin= (unsigned short*)(ws + (size_t)33554432);
    unsigned short* P    = (unsigned short*)(ws);
    unsigned short* qb   = (unsigned short*)(ws + (size_t)67108864);
    unsigned short* kb   = (unsigned short*)(ws + (size_t)100663296);
    unsigned short* vt   = (unsigned short*)(ws + (size_t)134217728);
    unsigned short* Wt   = (unsigned short*)(ws + (size_t)167772160);
    float*          Ppart= (float*)(ws + (size_t)174063616);
    float*          rs   = (float*)(ws + (size_t)175112192);

    convert_in<<<4096, 256, 0, stream>>>(q_in, k_v, qbin, kvbin);
    convert_w<<<dim3(256, 3), 256, 0, stream>>>(Wq, Wk, Wv, Wt);
    proj_q256<<<256, 512, 0, stream>>>(Wt, qbin, bq, qb);
    proj_kv256<<<512, 512, 0, stream>>>(kvbin, Wt + (size_t)EMB * EMB, bk, bv, kb, vt);
    qk256_kernel<<<512, 512, 0, stream>>>(qb, kb, P, Ppart);
    rowsum_final<<<64, 256, 0, stream>>>(Ppart, rs);
    pv256_kernel<<<256, 512, 0, stream>>>(P, vt, rs, out);
}

// Round 7
// 311.547 us; speedup vs baseline: 1.1797x; 1.0116x over previous
//
#include <hip/hip_runtime.h>
#include <hip/hip_bf16.h>

// CrossAttention: q = q_in@Wq+bq; k = k_v@Wk+bk; v = k_v@Wv+bv
// S = q@k^T * EMBED^-0.5 ; P = softmax(S) ; out = P@v
// B=8, I=J=2048, D=1024. All f32 in/out; internal compute bf16 MFMA.

#define BATCH 8
#define SEQ   2048
#define EMB   1024
#define SC2   0.045084222f         // EMB^-0.5 * log2(e)

typedef __attribute__((ext_vector_type(8))) short bf16x8;
typedef __attribute__((ext_vector_type(4))) float f32x4;
typedef __attribute__((ext_vector_type(4))) unsigned short u16x4;
typedef __attribute__((ext_vector_type(8))) unsigned short u16x8;
typedef __attribute__((ext_vector_type(4))) float fl4;

__device__ __forceinline__ unsigned short f2bf(float f) {
    unsigned u = __builtin_bit_cast(unsigned, f);
    unsigned r = u + 0x7fffu + ((u >> 16) & 1u);   // RNE
    return (unsigned short)(r >> 16);
}
__device__ __forceinline__ float bf2f(unsigned short s) {
    return __builtin_bit_cast(float, ((unsigned)s) << 16);
}
__device__ __forceinline__ void gload16(const unsigned short* g, unsigned short* l) {
    __builtin_amdgcn_global_load_lds(
        (const __attribute__((address_space(1))) void*)g,
        (__attribute__((address_space(3))) void*)l, 16, 0, 0);
}

// ---------------------------------------------------------------------------
// convert_all: blocks [0,4096) convert q_in/k_v f32->bf16;
// blocks [4096,4864) convert+transpose Wq|Wk|Wv -> Wt [n][k] bf16.
// ---------------------------------------------------------------------------
__global__ __launch_bounds__(256)
void convert_all(const float* __restrict__ q_in, const float* __restrict__ k_v,
                 const float* __restrict__ Wq, const float* __restrict__ Wk,
                 const float* __restrict__ Wv,
                 unsigned short* __restrict__ qbin, unsigned short* __restrict__ kvbin,
                 unsigned short* __restrict__ Wt)
{
    const int bid = blockIdx.x;
    const int tid = threadIdx.x;
    if (bid < 4096) {
        const size_t N = (size_t)BATCH * SEQ * EMB;
        size_t idx = ((size_t)bid * 256 + tid) * 8;
        const size_t stride = (size_t)4096 * 256 * 8;
        for (; idx < N; idx += stride) {
            fl4 a0 = *(const fl4*)&q_in[idx];
            fl4 a1 = *(const fl4*)&q_in[idx + 4];
            fl4 b0 = *(const fl4*)&k_v[idx];
            fl4 b1 = *(const fl4*)&k_v[idx + 4];
            u16x8 ua, ub;
#pragma unroll
            for (int i = 0; i < 4; i++) {
                ua[i] = f2bf(a0[i]); ua[i + 4] = f2bf(a1[i]);
                ub[i] = f2bf(b0[i]); ub[i + 4] = f2bf(b1[i]);
            }
            *(u16x8*)&qbin[idx] = ua;
            *(u16x8*)&kvbin[idx] = ub;
        }
    } else {
        const int b2 = bid - 4096;              // 768 blocks
        const int wsel = b2 >> 8, rest = b2 & 255;
        const float* W = (wsel == 0) ? Wq : (wsel == 1) ? Wk : Wv;
        unsigned short* O = Wt + (size_t)wsel * EMB * EMB;
        const int k0 = (rest >> 4) * 64;
        const int n0 = (rest & 15) * 64;
        __shared__ unsigned short l[64 * 65];
#pragma unroll
        for (int it = 0; it < 16; it++) {
            const int lin = it * 256 + tid;
            const int k = lin >> 6, n = lin & 63;
            l[n * 65 + k] = f2bf(W[(size_t)(k0 + k) * EMB + n0 + n]);
        }
        __syncthreads();
#pragma unroll
        for (int it = 0; it < 16; it++) {
            const int lin = it * 256 + tid;
            const int n = lin >> 6, k = lin & 63;
            O[(size_t)(n0 + n) * EMB + k0 + k] = l[n * 65 + k];
        }
    }
}

// ---------------------------------------------------------------------------
// Shared deep-pipelined 256x256 GEMM core (BK=32, 8 waves, 4-slot LDS ring).
// LDS tile [256][32] bf16 (64 B rows): aggregate-conflict-free ds_read_b128.
// 2-barrier K-tile (r7): read ALL 12 frags pre-barrier (slot stable for the
// whole tile), MFMA cluster1, stage B, MFMA cluster2, vmcnt(4), barrier.
// Ring discipline (proven r4): tile T staged during tile T-2; at end of tile
// T wait vmcnt(4) -> T+1's 4 stage-issues landed; closing barrier publishes
// each wave's landed stages to all readers.
// ---------------------------------------------------------------------------
__device__ __forceinline__ void stageT(const unsigned short* lanebase, size_t rstride,
                                       unsigned short* lwave) {
#pragma unroll
    for (int i = 0; i < 2; i++)
        gload16(lanebase + (size_t)(i * 128) * rstride, lwave + i * 4096);
}

#define PIPE_TILE(SLOT, DO_STAGE, STAGE_A_BASE, STAGE_A_LDS, STAGE_B_BASE, STAGE_B_LDS) \
    {                                                                           \
        const unsigned short* pa = &sA[SLOT][0];                                \
        const unsigned short* pb = &sB[SLOT][0];                                \
        bf16x8 a0 = *(bf16x8*)&pa[aoff0];                                       \
        bf16x8 a1 = *(bf16x8*)&pa[aoff0 + 512];                                 \
        bf16x8 a2 = *(bf16x8*)&pa[aoff0 + 1024];                                \
        bf16x8 a3 = *(bf16x8*)&pa[aoff0 + 1536];                                \
        bf16x8 a4 = *(bf16x8*)&pa[aoff0 + 2048];                                \
        bf16x8 a5 = *(bf16x8*)&pa[aoff0 + 2560];                                \
        bf16x8 a6 = *(bf16x8*)&pa[aoff0 + 3072];                                \
        bf16x8 a7 = *(bf16x8*)&pa[aoff0 + 3584];                                \
        bf16x8 bv0 = *(bf16x8*)&pb[boff0];                                      \
        bf16x8 bv1 = *(bf16x8*)&pb[boff0 + 512];                                \
        bf16x8 bv2 = *(bf16x8*)&pb[boff0 + 1024];                               \
        bf16x8 bv3 = *(bf16x8*)&pb[boff0 + 1536];                               \
        if (DO_STAGE) stageT(STAGE_A_BASE, strideA, STAGE_A_LDS);               \
        __builtin_amdgcn_s_barrier();                                           \
        asm volatile("s_waitcnt lgkmcnt(0)" ::: "memory");                      \
        __builtin_amdgcn_sched_barrier(0);                                      \
        __builtin_amdgcn_s_setprio(1);                                          \
        acc[0][0] = __builtin_amdgcn_mfma_f32_16x16x32_bf16(a0, bv0, acc[0][0], 0, 0, 0); \
        acc[0][1] = __builtin_amdgcn_mfma_f32_16x16x32_bf16(a0, bv1, acc[0][1], 0, 0, 0); \
        acc[0][2] = __builtin_amdgcn_mfma_f32_16x16x32_bf16(a0, bv2, acc[0][2], 0, 0, 0); \
        acc[0][3] = __builtin_amdgcn_mfma_f32_16x16x32_bf16(a0, bv3, acc[0][3], 0, 0, 0); \
        acc[1][0] = __builtin_amdgcn_mfma_f32_16x16x32_bf16(a1, bv0, acc[1][0], 0, 0, 0); \
        acc[1][1] = __builtin_amdgcn_mfma_f32_16x16x32_bf16(a1, bv1, acc[1][1], 0, 0, 0); \
        acc[1][2] = __builtin_amdgcn_mfma_f32_16x16x32_bf16(a1, bv2, acc[1][2], 0, 0, 0); \
        acc[1][3] = __builtin_amdgcn_mfma_f32_16x16x32_bf16(a1, bv3, acc[1][3], 0, 0, 0); \
        acc[2][0] = __builtin_amdgcn_mfma_f32_16x16x32_bf16(a2, bv0, acc[2][0], 0, 0, 0); \
        acc[2][1] = __builtin_amdgcn_mfma_f32_16x16x32_bf16(a2, bv1, acc[2][1], 0, 0, 0); \
        acc[2][2] = __builtin_amdgcn_mfma_f32_16x16x32_bf16(a2, bv2, acc[2][2], 0, 0, 0); \
        acc[2][3] = __builtin_amdgcn_mfma_f32_16x16x32_bf16(a2, bv3, acc[2][3], 0, 0, 0); \
        acc[3][0] = __builtin_amdgcn_mfma_f32_16x16x32_bf16(a3, bv0, acc[3][0], 0, 0, 0); \
        acc[3][1] = __builtin_amdgcn_mfma_f32_16x16x32_bf16(a3, bv1, acc[3][1], 0, 0, 0); \
        acc[3][2] = __builtin_amdgcn_mfma_f32_16x16x32_bf16(a3, bv2, acc[3][2], 0, 0, 0); \
        acc[3][3] = __builtin_amdgcn_mfma_f32_16x16x32_bf16(a3, bv3, acc[3][3], 0, 0, 0); \
        __builtin_amdgcn_s_setprio(0);                                          \
        if (DO_STAGE) stageT(STAGE_B_BASE, strideB, STAGE_B_LDS);               \
        __builtin_amdgcn_s_setprio(1);                                          \
        acc[4][0] = __builtin_amdgcn_mfma_f32_16x16x32_bf16(a4, bv0, acc[4][0], 0, 0, 0); \
        acc[4][1] = __builtin_amdgcn_mfma_f32_16x16x32_bf16(a4, bv1, acc[4][1], 0, 0, 0); \
        acc[4][2] = __builtin_amdgcn_mfma_f32_16x16x32_bf16(a4, bv2, acc[4][2], 0, 0, 0); \
        acc[4][3] = __builtin_amdgcn_mfma_f32_16x16x32_bf16(a4, bv3, acc[4][3], 0, 0, 0); \
        acc[5][0] = __builtin_amdgcn_mfma_f32_16x16x32_bf16(a5, bv0, acc[5][0], 0, 0, 0); \
        acc[5][1] = __builtin_amdgcn_mfma_f32_16x16x32_bf16(a5, bv1, acc[5][1], 0, 0, 0); \
        acc[5][2] = __builtin_amdgcn_mfma_f32_16x16x32_bf16(a5, bv2, acc[5][2], 0, 0, 0); \
        acc[5][3] = __builtin_amdgcn_mfma_f32_16x16x32_bf16(a5, bv3, acc[5][3], 0, 0, 0); \
        acc[6][0] = __builtin_amdgcn_mfma_f32_16x16x32_bf16(a6, bv0, acc[6][0], 0, 0, 0); \
        acc[6][1] = __builtin_amdgcn_mfma_f32_16x16x32_bf16(a6, bv1, acc[6][1], 0, 0, 0); \
        acc[6][2] = __builtin_amdgcn_mfma_f32_16x16x32_bf16(a6, bv2, acc[6][2], 0, 0, 0); \
        acc[6][3] = __builtin_amdgcn_mfma_f32_16x16x32_bf16(a6, bv3, acc[6][3], 0, 0, 0); \
        acc[7][0] = __builtin_amdgcn_mfma_f32_16x16x32_bf16(a7, bv0, acc[7][0], 0, 0, 0); \
        acc[7][1] = __builtin_amdgcn_mfma_f32_16x16x32_bf16(a7, bv1, acc[7][1], 0, 0, 0); \
        acc[7][2] = __builtin_amdgcn_mfma_f32_16x16x32_bf16(a7, bv2, acc[7][2], 0, 0, 0); \
        acc[7][3] = __builtin_amdgcn_mfma_f32_16x16x32_bf16(a7, bv3, acc[7][3], 0, 0, 0); \
        __builtin_amdgcn_s_setprio(0);                                          \
        asm volatile("s_waitcnt vmcnt(4)" ::: "memory");                        \
        __builtin_amdgcn_s_barrier();                                           \
        __builtin_amdgcn_sched_barrier(0);                                      \
    }

__device__ __forceinline__ void pipe_gemm(
    const unsigned short* __restrict__ Asrc,
    const unsigned short* __restrict__ Bsrc,
    const size_t strideA, const size_t strideB, const int NT,
    unsigned short (*sA)[8192], unsigned short (*sB)[8192],
    const int lwave, const int aoff0, const int boff0,
    f32x4 acc[8][4])
{
    stageT(Asrc, strideA, &sA[0][lwave]);
    stageT(Bsrc, strideB, &sB[0][lwave]);
    stageT(Asrc + 32, strideA, &sA[1][lwave]);
    stageT(Bsrc + 32, strideB, &sB[1][lwave]);
    asm volatile("s_waitcnt vmcnt(4)" ::: "memory");
    __builtin_amdgcn_s_barrier();
    __builtin_amdgcn_sched_barrier(0);

    for (int T = 0; T < NT; ++T) {
        const int s = T & 3;
        const int doStage = (T + 2 < NT);
        const int s2 = (T + 2) & 3;
        PIPE_TILE(s, doStage, Asrc + (T + 2) * 32, &sA[s2][lwave],
                  Bsrc + (T + 2) * 32, &sB[s2][lwave]);
    }
}

#define PIPE_PREAMBLE                                                     \
    __shared__ unsigned short sMem[65536];  /* 128 KB */                  \
    unsigned short (*sA)[8192] = (unsigned short (*)[8192])sMem;          \
    unsigned short (*sB)[8192] = (unsigned short (*)[8192])(sMem + 32768);\
    const int tid = threadIdx.x, lane = tid & 63;                         \
    const int wid = tid >> 6, wr = wid >> 2, wn = wid & 3;                \
    const int r = lane & 15, g = lane >> 4;                               \
    const int lwave = (wid << 9);                                         \
    const int aoff0 = (wr * 128 + r) * 32 + g * 8;                        \
    const int boff0 = (wn * 64 + r) * 32 + g * 8;                         \
    f32x4 acc[8][4];                                                      \
    _Pragma("unroll") for (int i_ = 0; i_ < 8; i_++)                      \
    _Pragma("unroll") for (int j_ = 0; j_ < 4; j_++) acc[i_][j_] = (f32x4)0.0f;

// Coalesced flush of a [256 row][512 B] swizzled LDS tile to global.
__device__ __forceinline__ void lds_flush_bf16(const unsigned short* sP,
                                               unsigned short* gbase,
                                               size_t gstride, int tid)
{
    const int lane = tid & 63, wv = tid >> 6;
    const int rowsel = lane >> 5, jj = lane & 31;
#pragma unroll
    for (int it = 0; it < 16; ++it) {
        const int row = it * 16 + wv * 2 + rowsel;
        const int byte = row * 512 + ((jj * 16) ^ ((row & 7) << 4));
        u16x8 v = *(const u16x8*)((const char*)sP + byte);
        *(u16x8*)&gbase[(size_t)row * gstride + jj * 8] = v;
    }
}

// ---------------------------------------------------------------------------
// proj_all: blocks [0,256) = q-projection (swapped: A=WqT d-rows, B=qbin
// i-rows); blocks [256,768) = kv-projection (A=kvbin i-rows, B=WkvT n-rows).
// ---------------------------------------------------------------------------
__global__ __launch_bounds__(512, 1)
void proj_all(const unsigned short* __restrict__ Wt,
              const unsigned short* __restrict__ qbin,
              const unsigned short* __restrict__ kvbin,
              const float* __restrict__ bq, const float* __restrict__ bk,
              const float* __restrict__ bv,
              unsigned short* __restrict__ qb, unsigned short* __restrict__ kb,
              unsigned short* __restrict__ vt)
{
    PIPE_PREAMBLE
    const int bid = blockIdx.x;
    const size_t strideA = EMB, strideB = EMB;
    const unsigned short* Asrc;
    const unsigned short* Bsrc;
    int d0 = 0, i0 = 0, m0 = 0, n0 = 0;
    const bool qrole = (bid < 256);
    if (qrole) {
        const int lid = (bid & 7) * 32 + (bid >> 3);
        d0 = (lid & 3) * 256; i0 = (lid >> 2) * 256;
        Asrc = Wt + (size_t)(d0 + (tid >> 2)) * EMB + (tid & 3) * 8;
        Bsrc = qbin + (size_t)(i0 + (tid >> 2)) * EMB + (tid & 3) * 8;
    } else {
        const int b2 = bid - 256;
        const int lid = (b2 & 7) * 64 + (b2 >> 3);
        n0 = (lid & 7) * 256; m0 = (lid >> 3) * 256;
        Asrc = kvbin + (size_t)(m0 + (tid >> 2)) * EMB + (tid & 3) * 8;
        Bsrc = Wt + (size_t)EMB * EMB + (size_t)(n0 + (tid >> 2)) * EMB + (tid & 3) * 8;
    }

    pipe_gemm(Asrc, Bsrc, strideA, strideB, EMB / 32, sA, sB, lwave, aoff0, boff0, acc);

    if (qrole) {
        // LDS transpose: row = i-local (wn,n,r), col = d-local (wr,mm,g,c)
#pragma unroll
        for (int mm = 0; mm < 8; mm++) {
            const int colb = wr * 128 + mm * 16 + g * 4;
            const fl4 b4 = *(const fl4*)&bq[d0 + colb];
#pragma unroll
            for (int n = 0; n < 4; n++) {
                const int row = wn * 64 + n * 16 + r;
                u16x4 u;
#pragma unroll
                for (int c = 0; c < 4; c++) u[c] = f2bf(acc[mm][n][c] + b4[c]);
                const int byte = row * 512 + ((colb * 2) ^ ((row & 7) << 4));
                *(u16x4*)((char*)sMem + byte) = u;
            }
        }
        __syncthreads();
        lds_flush_bf16(sMem, qb + (size_t)i0 * EMB + d0, EMB, tid);
    } else {
        const int b = m0 >> 11;                 // batch of this 256-row i-tile
        const int j0l = m0 & 2047;
        if (n0 < 1024) {                        // k-output (block-uniform)
#pragma unroll
            for (int mm = 0; mm < 8; mm++) {
                const int ibase = m0 + wr * 128 + mm * 16 + g * 4;
#pragma unroll
                for (int n = 0; n < 4; n++) {
                    const int col = n0 + wn * 64 + n * 16 + r;
                    const float bb = bk[col];
#pragma unroll
                    for (int c = 0; c < 4; c++)
                        kb[(size_t)(ibase + c) * EMB + col] = f2bf(acc[mm][n][c] + bb);
                }
            }
        } else {                                // v-output: LDS transpose
#pragma unroll
            for (int mm = 0; mm < 8; mm++) {
                const int colb = wr * 128 + mm * 16 + g * 4;
#pragma unroll
                for (int n = 0; n < 4; n++) {
                    const int row = wn * 64 + n * 16 + r;
                    const float bb = bv[n0 - 1024 + row];
                    u16x4 u;
#pragma unroll
                    for (int c = 0; c < 4; c++) u[c] = f2bf(acc[mm][n][c] + bb);
                    const int byte = row * 512 + ((colb * 2) ^ ((row & 7) << 4));
                    *(u16x4*)((char*)sMem + byte) = u;
                }
            }
            __syncthreads();
            lds_flush_bf16(sMem, vt + ((size_t)b * EMB + (n0 - 1024)) * SEQ + j0l,
                           SEQ, tid);
        }
    }
}

// ---------------------------------------------------------------------------
// qk (swapped): A = kb rows (j), B = qb rows (i). P[i][j] = exp2(S*sc) via
// LDS transpose; partial rowsums (16 slots) to Ppart.
// ---------------------------------------------------------------------------
__global__ __launch_bounds__(512, 1)
void qk256_kernel(const unsigned short* __restrict__ qb,
                  const unsigned short* __restrict__ kb,
                  unsigned short* __restrict__ P,
                  float* __restrict__ Ppart)
{
    PIPE_PREAMBLE
    const int bid = blockIdx.x;                 // 512 blocks
    const int lid = (bid & 7) * 64 + (bid >> 3);
    const int b = lid >> 6, jt = (lid >> 3) & 7, it = lid & 7;
    const int j0 = jt * 256, i0 = it * 256;
    const size_t strideA = EMB, strideB = EMB;
    const unsigned short* Ag = kb + (size_t)b * SEQ * EMB;
    const unsigned short* Bg = qb + (size_t)b * SEQ * EMB;
    const unsigned short* Asrc = Ag + (size_t)(j0 + (tid >> 2)) * EMB + (tid & 3) * 8;
    const unsigned short* Bsrc = Bg + (size_t)(i0 + (tid >> 2)) * EMB + (tid & 3) * 8;

    pipe_gemm(Asrc, Bsrc, strideA, strideB, EMB / 32, sA, sB, lwave, aoff0, boff0, acc);

    // LDS transpose: row = i-local (wn,n,r), col = j-local (wr,mm,g,c)
    float ps[4] = {0.f, 0.f, 0.f, 0.f};
#pragma unroll
    for (int mm = 0; mm < 8; mm++) {
        const int colb = wr * 128 + mm * 16 + g * 4;
#pragma unroll
        for (int n = 0; n < 4; n++) {
            const int row = wn * 64 + n * 16 + r;
            u16x4 u;
#pragma unroll
            for (int c = 0; c < 4; c++) {
                const float p = exp2f(acc[mm][n][c] * SC2);   // no max-sub: |S|<~6
                ps[n] += p;
                u[c] = f2bf(p);
            }
            const int byte = row * 512 + ((colb * 2) ^ ((row & 7) << 4));
            *(u16x4*)((char*)sMem + byte) = u;
        }
    }
    // partial rowsums: reduce over g (j-direction)
#pragma unroll
    for (int n = 0; n < 4; n++) {
        ps[n] += __shfl_xor(ps[n], 16);
        ps[n] += __shfl_xor(ps[n], 32);
    }
    if (g == 0) {
        const int slot = jt * 2 + wr;
        float* pp = Ppart + (size_t)slot * (BATCH * SEQ) + (size_t)b * SEQ;
#pragma unroll
        for (int n = 0; n < 4; n++)
            pp[i0 + wn * 64 + n * 16 + r] = ps[n];
    }
    __syncthreads();
    unsigned short* Pb = P + (size_t)b * SEQ * SEQ;
    lds_flush_bf16(sMem, Pb + (size_t)i0 * SEQ + j0, SEQ, tid);
}

// ---------------------------------------------------------------------------
// pv (swapped): A = vt rows (d), B = P rows (i). Rowsum finalize fused into
// the prologue (sums 16 Ppart slots per owned row). out[i][d] f32 via LDS
// transpose in two chunks.
// ---------------------------------------------------------------------------
__global__ __launch_bounds__(512, 1)
void pv256_kernel(const unsigned short* __restrict__ P,
                  const unsigned short* __restrict__ vt,
                  const float* __restrict__ Ppart,
                  float* __restrict__ out)
{
    PIPE_PREAMBLE
    const int bid = blockIdx.x;                 // 256 blocks
    const int lid = (bid & 7) * 32 + (bid >> 3);
    const int b = lid >> 5, it = (lid >> 2) & 7, dt = lid & 3;
    const int d0 = dt * 256, i0 = it * 256;
    const size_t strideA = SEQ, strideB = SEQ;
    const unsigned short* Ag = vt + (size_t)b * EMB * SEQ;
    const unsigned short* Bg = P + (size_t)b * SEQ * SEQ;
    const unsigned short* Asrc = Ag + (size_t)(d0 + (tid >> 2)) * SEQ + (tid & 3) * 8;
    const unsigned short* Bsrc = Bg + (size_t)(i0 + (tid >> 2)) * SEQ + (tid & 3) * 8;

    // fused rowsum finalize: inv[n] for this thread's 4 owned i-rows
    float inv[4];
#pragma unroll
    for (int n = 0; n < 4; n++) {
        const int row = (size_t)0 + b * SEQ + i0 + wn * 64 + n * 16 + r;
        float s = 0.f;
#pragma unroll
        for (int slot = 0; slot < 16; slot++)
            s += Ppart[(size_t)slot * (BATCH * SEQ) + row];
        inv[n] = 1.0f / s;
    }

    pipe_gemm(Asrc, Bsrc, strideA, strideB, SEQ / 32, sA, sB, lwave, aoff0, boff0, acc);

    float* ob = out + (size_t)b * SEQ * EMB;
    float* sF = (float*)sMem;   // [256 rows][128 f32] per chunk
#pragma unroll
    for (int h = 0; h < 2; h++) {
        if (wr == h) {
            // row = i-local (wn,n,r), col = d-local within chunk (mm,g,c)
#pragma unroll
            for (int mm = 0; mm < 8; mm++) {
                const int colb = mm * 16 + g * 4;      // 0..127
#pragma unroll
                for (int n = 0; n < 4; n++) {
                    const int row = wn * 64 + n * 16 + r;
                    fl4 o;
#pragma unroll
                    for (int c = 0; c < 4; c++) o[c] = acc[mm][n][c] * inv[n];
                    const int byte = row * 512 + ((colb * 4) ^ ((row & 7) << 4));
                    *(fl4*)((char*)sF + byte) = o;
                }
            }
        }
        __syncthreads();
        {
            const int rowsel = lane >> 5, jj = lane & 31;
#pragma unroll
            for (int itx = 0; itx < 16; ++itx) {
                const int row = itx * 16 + wid * 2 + rowsel;
                const int byte = row * 512 + ((jj * 16) ^ ((row & 7) << 4));
                fl4 v = *(const fl4*)((const char*)sF + byte);
                *(fl4*)&ob[(size_t)(i0 + row) * EMB + d0 + h * 128 + jj * 4] = v;
            }
        }
        if (h == 0) __syncthreads();
    }
}

// ---------------------------------------------------------------------------
extern "C" void kernel_launch(void* const* d_in, const int* in_sizes, int n_in,
                              void* d_out, int out_size, void* d_ws, size_t ws_size,
                              hipStream_t stream)
{
    const float* q_in = (const float*)d_in[0];
    const float* k_v  = (const float*)d_in[1];
    const float* Wq   = (const float*)d_in[2];
    const float* bq   = (const float*)d_in[3];
    const float* Wk   = (const float*)d_in[4];
    const float* bk   = (const float*)d_in[5];
    const float* Wv   = (const float*)d_in[6];
    const float* bv   = (const float*)d_in[7];
    float* out = (float*)d_out;

    // workspace layout (bytes):
    //   qbin  bf16 [8][2048][1024] @ 0      -- dead after proj_all
    //   kvbin bf16 [8][2048][1024] @ 32 MB  -- dead after proj_all
    //   P     bf16 [8][2048][2048] @ 0      -- aliases qbin+kvbin
    //   qb @ 64 MB ; kb @ 96 MB ; vt @ 128 MB ; Wt (WqT|WkT|WvT) @ 160 MB
    //   Ppart f32 [16][16384] @ 166 MB
    char* ws = (char*)d_ws;
    unsigned short* qbin = (unsigned short*)(ws);
    unsigned short* kvbin= (unsigned short*)(ws + (size_t)33554432);
    unsigned short* P    = (unsigned short*)(ws);
    unsigned short* qb   = (unsigned short*)(ws + (size_t)67108864);
    unsigned short* kb   = (unsigned short*)(ws + (size_t)100663296);
    unsigned short* vt   = (unsigned short*)(ws + (size_t)134217728);
    unsigned short* Wt   = (unsigned short*)(ws + (size_t)167772160);
    float*          Ppart= (float*)(ws + (size_t)174063616);

    convert_all<<<4864, 256, 0, stream>>>(q_in, k_v, Wq, Wk, Wv, qbin, kvbin, Wt);
    proj_all<<<768, 512, 0, stream>>>(Wt, qbin, kvbin, bq, bk, bv, qb, kb, vt);
    qk256_kernel<<<512, 512, 0, stream>>>(qb, kb, P, Ppart);
    pv256_kernel<<<256, 512, 0, stream>>>(P, vt, Ppart, out);
}

// Round 8
// 301.626 us; speedup vs baseline: 1.2185x; 1.0329x over previous
//
#include <hip/hip_runtime.h>
#include <hip/hip_bf16.h>

// CrossAttention: q = q_in@Wq+bq; k = k_v@Wk+bk; v = k_v@Wv+bv
// S = q@k^T * EMBED^-0.5 ; P = softmax(S) ; out = P@v
// B=8, I=J=2048, D=1024. All f32 in/out; internal compute bf16 MFMA.

#define BATCH 8
#define SEQ   2048
#define EMB   1024
#define SC2   0.045084222f         // EMB^-0.5 * log2(e)

typedef __attribute__((ext_vector_type(8))) short bf16x8;
typedef __attribute__((ext_vector_type(4))) float f32x4;
typedef __attribute__((ext_vector_type(4))) unsigned short u16x4;
typedef __attribute__((ext_vector_type(8))) unsigned short u16x8;
typedef __attribute__((ext_vector_type(4))) float fl4;

__device__ __forceinline__ unsigned short f2bf(float f) {
    unsigned u = __builtin_bit_cast(unsigned, f);
    unsigned r = u + 0x7fffu + ((u >> 16) & 1u);   // RNE
    return (unsigned short)(r >> 16);
}
__device__ __forceinline__ float bf2f(unsigned short s) {
    return __builtin_bit_cast(float, ((unsigned)s) << 16);
}
__device__ __forceinline__ void gload16(const unsigned short* g, unsigned short* l) {
    __builtin_amdgcn_global_load_lds(
        (const __attribute__((address_space(1))) void*)g,
        (__attribute__((address_space(3))) void*)l, 16, 0, 0);
}

// ---------------------------------------------------------------------------
// convert_all: blocks [0,4096) convert q_in/k_v f32->bf16;
// blocks [4096,4864) convert+transpose Wq|Wk|Wv -> Wt [n][k] bf16.
// ---------------------------------------------------------------------------
__global__ __launch_bounds__(256)
void convert_all(const float* __restrict__ q_in, const float* __restrict__ k_v,
                 const float* __restrict__ Wq, const float* __restrict__ Wk,
                 const float* __restrict__ Wv,
                 unsigned short* __restrict__ qbin, unsigned short* __restrict__ kvbin,
                 unsigned short* __restrict__ Wt)
{
    const int bid = blockIdx.x;
    const int tid = threadIdx.x;
    if (bid < 4096) {
        const size_t N = (size_t)BATCH * SEQ * EMB;
        size_t idx = ((size_t)bid * 256 + tid) * 8;
        const size_t stride = (size_t)4096 * 256 * 8;
        for (; idx < N; idx += stride) {
            fl4 a0 = *(const fl4*)&q_in[idx];
            fl4 a1 = *(const fl4*)&q_in[idx + 4];
            fl4 b0 = *(const fl4*)&k_v[idx];
            fl4 b1 = *(const fl4*)&k_v[idx + 4];
            u16x8 ua, ub;
#pragma unroll
            for (int i = 0; i < 4; i++) {
                ua[i] = f2bf(a0[i]); ua[i + 4] = f2bf(a1[i]);
                ub[i] = f2bf(b0[i]); ub[i + 4] = f2bf(b1[i]);
            }
            *(u16x8*)&qbin[idx] = ua;
            *(u16x8*)&kvbin[idx] = ub;
        }
    } else {
        const int b2 = bid - 4096;              // 768 blocks
        const int wsel = b2 >> 8, rest = b2 & 255;
        const float* W = (wsel == 0) ? Wq : (wsel == 1) ? Wk : Wv;
        unsigned short* O = Wt + (size_t)wsel * EMB * EMB;
        const int k0 = (rest >> 4) * 64;
        const int n0 = (rest & 15) * 64;
        __shared__ unsigned short l[64 * 65];
#pragma unroll
        for (int it = 0; it < 16; it++) {
            const int lin = it * 256 + tid;
            const int k = lin >> 6, n = lin & 63;
            l[n * 65 + k] = f2bf(W[(size_t)(k0 + k) * EMB + n0 + n]);
        }
        __syncthreads();
#pragma unroll
        for (int it = 0; it < 16; it++) {
            const int lin = it * 256 + tid;
            const int n = lin >> 6, k = lin & 63;
            O[(size_t)(n0 + n) * EMB + k0 + k] = l[n * 65 + k];
        }
    }
}

// ---------------------------------------------------------------------------
// Shared deep-pipelined 256x256 GEMM core (BK=32, 8 waves, 4-slot LDS ring).
// LDS tile [256 rows][4 col16] bf16, COLUMN-SWIZZLED (r8): data for
// (row R, col16 c) lives at c' = c ^ ((R>>1)&3). Staging keeps the LDS dest
// linear (gload_lds) and pre-permutes the GLOBAL source column per lane
// (rule #21: inverse-swz source + swz read). This spreads each 32-lane
// b128 frag read across all 32 banks (was 16 -> ~2x LDS read throughput).
// 2-barrier K-tile (r7); ring discipline (proven r4): tile T staged during
// tile T-2; vmcnt(4) at end of tile T -> T+1's stages landed.
// ---------------------------------------------------------------------------
__device__ __forceinline__ void stageT(const unsigned short* lanebase, size_t rstride,
                                       unsigned short* lwave) {
#pragma unroll
    for (int i = 0; i < 2; i++)
        gload16(lanebase + (size_t)(i * 128) * rstride, lwave + i * 4096);
}

#define PIPE_TILE(SLOT, DO_STAGE, STAGE_A_BASE, STAGE_A_LDS, STAGE_B_BASE, STAGE_B_LDS) \
    {                                                                           \
        const unsigned short* pa = &sA[SLOT][0];                                \
        const unsigned short* pb = &sB[SLOT][0];                                \
        bf16x8 a0 = *(bf16x8*)&pa[aoff0];                                       \
        bf16x8 a1 = *(bf16x8*)&pa[aoff0 + 512];                                 \
        bf16x8 a2 = *(bf16x8*)&pa[aoff0 + 1024];                                \
        bf16x8 a3 = *(bf16x8*)&pa[aoff0 + 1536];                                \
        bf16x8 a4 = *(bf16x8*)&pa[aoff0 + 2048];                                \
        bf16x8 a5 = *(bf16x8*)&pa[aoff0 + 2560];                                \
        bf16x8 a6 = *(bf16x8*)&pa[aoff0 + 3072];                                \
        bf16x8 a7 = *(bf16x8*)&pa[aoff0 + 3584];                                \
        bf16x8 bv0 = *(bf16x8*)&pb[boff0];                                      \
        bf16x8 bv1 = *(bf16x8*)&pb[boff0 + 512];                                \
        bf16x8 bv2 = *(bf16x8*)&pb[boff0 + 1024];                               \
        bf16x8 bv3 = *(bf16x8*)&pb[boff0 + 1536];                               \
        if (DO_STAGE) stageT(STAGE_A_BASE, strideA, STAGE_A_LDS);               \
        __builtin_amdgcn_s_barrier();                                           \
        asm volatile("s_waitcnt lgkmcnt(0)" ::: "memory");                      \
        __builtin_amdgcn_sched_barrier(0);                                      \
        __builtin_amdgcn_s_setprio(1);                                          \
        acc[0][0] = __builtin_amdgcn_mfma_f32_16x16x32_bf16(a0, bv0, acc[0][0], 0, 0, 0); \
        acc[0][1] = __builtin_amdgcn_mfma_f32_16x16x32_bf16(a0, bv1, acc[0][1], 0, 0, 0); \
        acc[0][2] = __builtin_amdgcn_mfma_f32_16x16x32_bf16(a0, bv2, acc[0][2], 0, 0, 0); \
        acc[0][3] = __builtin_amdgcn_mfma_f32_16x16x32_bf16(a0, bv3, acc[0][3], 0, 0, 0); \
        acc[1][0] = __builtin_amdgcn_mfma_f32_16x16x32_bf16(a1, bv0, acc[1][0], 0, 0, 0); \
        acc[1][1] = __builtin_amdgcn_mfma_f32_16x16x32_bf16(a1, bv1, acc[1][1], 0, 0, 0); \
        acc[1][2] = __builtin_amdgcn_mfma_f32_16x16x32_bf16(a1, bv2, acc[1][2], 0, 0, 0); \
        acc[1][3] = __builtin_amdgcn_mfma_f32_16x16x32_bf16(a1, bv3, acc[1][3], 0, 0, 0); \
        acc[2][0] = __builtin_amdgcn_mfma_f32_16x16x32_bf16(a2, bv0, acc[2][0], 0, 0, 0); \
        acc[2][1] = __builtin_amdgcn_mfma_f32_16x16x32_bf16(a2, bv1, acc[2][1], 0, 0, 0); \
        acc[2][2] = __builtin_amdgcn_mfma_f32_16x16x32_bf16(a2, bv2, acc[2][2], 0, 0, 0); \
        acc[2][3] = __builtin_amdgcn_mfma_f32_16x16x32_bf16(a2, bv3, acc[2][3], 0, 0, 0); \
        acc[3][0] = __builtin_amdgcn_mfma_f32_16x16x32_bf16(a3, bv0, acc[3][0], 0, 0, 0); \
        acc[3][1] = __builtin_amdgcn_mfma_f32_16x16x32_bf16(a3, bv1, acc[3][1], 0, 0, 0); \
        acc[3][2] = __builtin_amdgcn_mfma_f32_16x16x32_bf16(a3, bv2, acc[3][2], 0, 0, 0); \
        acc[3][3] = __builtin_amdgcn_mfma_f32_16x16x32_bf16(a3, bv3, acc[3][3], 0, 0, 0); \
        __builtin_amdgcn_s_setprio(0);                                          \
        if (DO_STAGE) stageT(STAGE_B_BASE, strideB, STAGE_B_LDS);               \
        __builtin_amdgcn_s_setprio(1);                                          \
        acc[4][0] = __builtin_amdgcn_mfma_f32_16x16x32_bf16(a4, bv0, acc[4][0], 0, 0, 0); \
        acc[4][1] = __builtin_amdgcn_mfma_f32_16x16x32_bf16(a4, bv1, acc[4][1], 0, 0, 0); \
        acc[4][2] = __builtin_amdgcn_mfma_f32_16x16x32_bf16(a4, bv2, acc[4][2], 0, 0, 0); \
        acc[4][3] = __builtin_amdgcn_mfma_f32_16x16x32_bf16(a4, bv3, acc[4][3], 0, 0, 0); \
        acc[5][0] = __builtin_amdgcn_mfma_f32_16x16x32_bf16(a5, bv0, acc[5][0], 0, 0, 0); \
        acc[5][1] = __builtin_amdgcn_mfma_f32_16x16x32_bf16(a5, bv1, acc[5][1], 0, 0, 0); \
        acc[5][2] = __builtin_amdgcn_mfma_f32_16x16x32_bf16(a5, bv2, acc[5][2], 0, 0, 0); \
        acc[5][3] = __builtin_amdgcn_mfma_f32_16x16x32_bf16(a5, bv3, acc[5][3], 0, 0, 0); \
        acc[6][0] = __builtin_amdgcn_mfma_f32_16x16x32_bf16(a6, bv0, acc[6][0], 0, 0, 0); \
        acc[6][1] = __builtin_amdgcn_mfma_f32_16x16x32_bf16(a6, bv1, acc[6][1], 0, 0, 0); \
        acc[6][2] = __builtin_amdgcn_mfma_f32_16x16x32_bf16(a6, bv2, acc[6][2], 0, 0, 0); \
        acc[6][3] = __builtin_amdgcn_mfma_f32_16x16x32_bf16(a6, bv3, acc[6][3], 0, 0, 0); \
        acc[7][0] = __builtin_amdgcn_mfma_f32_16x16x32_bf16(a7, bv0, acc[7][0], 0, 0, 0); \
        acc[7][1] = __builtin_amdgcn_mfma_f32_16x16x32_bf16(a7, bv1, acc[7][1], 0, 0, 0); \
        acc[7][2] = __builtin_amdgcn_mfma_f32_16x16x32_bf16(a7, bv2, acc[7][2], 0, 0, 0); \
        acc[7][3] = __builtin_amdgcn_mfma_f32_16x16x32_bf16(a7, bv3, acc[7][3], 0, 0, 0); \
        __builtin_amdgcn_s_setprio(0);                                          \
        asm volatile("s_waitcnt vmcnt(4)" ::: "memory");                        \
        __builtin_amdgcn_s_barrier();                                           \
        __builtin_amdgcn_sched_barrier(0);                                      \
    }

__device__ __forceinline__ void pipe_gemm(
    const unsigned short* __restrict__ Asrc,
    const unsigned short* __restrict__ Bsrc,
    const size_t strideA, const size_t strideB, const int NT,
    unsigned short (*sA)[8192], unsigned short (*sB)[8192],
    const int lwave, const int aoff0, const int boff0,
    f32x4 acc[8][4])
{
    stageT(Asrc, strideA, &sA[0][lwave]);
    stageT(Bsrc, strideB, &sB[0][lwave]);
    stageT(Asrc + 32, strideA, &sA[1][lwave]);
    stageT(Bsrc + 32, strideB, &sB[1][lwave]);
    asm volatile("s_waitcnt vmcnt(4)" ::: "memory");
    __builtin_amdgcn_s_barrier();
    __builtin_amdgcn_sched_barrier(0);

    for (int T = 0; T < NT; ++T) {
        const int s = T & 3;
        const int doStage = (T + 2 < NT);
        const int s2 = (T + 2) & 3;
        PIPE_TILE(s, doStage, Asrc + (T + 2) * 32, &sA[s2][lwave],
                  Bsrc + (T + 2) * 32, &sB[s2][lwave]);
    }
}

// scol: swizzled source column (elems). Lane lands at LDS (R=tid>>2, c'=tid&3);
// it must fetch global col c = c' ^ ((R>>1)&3) = (tid&3) ^ ((tid>>3)&3).
// Frag read col for (row, g): c' = g ^ ((row>>1)&3); row>>1 bits reduce to
// (r>>1)&3 uniformly (wr*128, wn*64, mm*16, n*16 all vanish mod 4 after >>1).
#define PIPE_PREAMBLE                                                     \
    __shared__ unsigned short sMem[65536];  /* 128 KB */                  \
    unsigned short (*sA)[8192] = (unsigned short (*)[8192])sMem;          \
    unsigned short (*sB)[8192] = (unsigned short (*)[8192])(sMem + 32768);\
    const int tid = threadIdx.x, lane = tid & 63;                         \
    const int wid = tid >> 6, wr = wid >> 2, wn = wid & 3;                \
    const int r = lane & 15, g = lane >> 4;                               \
    const int lwave = (wid << 9);                                         \
    const int scol = ((tid & 3) ^ ((tid >> 3) & 3)) * 8;                  \
    const int gsw = (g ^ ((r >> 1) & 3)) * 8;                             \
    const int aoff0 = (wr * 128 + r) * 32 + gsw;                          \
    const int boff0 = (wn * 64 + r) * 32 + gsw;                           \
    f32x4 acc[8][4];                                                      \
    _Pragma("unroll") for (int i_ = 0; i_ < 8; i_++)                      \
    _Pragma("unroll") for (int j_ = 0; j_ < 4; j_++) acc[i_][j_] = (f32x4)0.0f;

// Coalesced flush of a [256 row][512 B] swizzled LDS tile to global.
__device__ __forceinline__ void lds_flush_bf16(const unsigned short* sP,
                                               unsigned short* gbase,
                                               size_t gstride, int tid)
{
    const int lane = tid & 63, wv = tid >> 6;
    const int rowsel = lane >> 5, jj = lane & 31;
#pragma unroll
    for (int it = 0; it < 16; ++it) {
        const int row = it * 16 + wv * 2 + rowsel;
        const int byte = row * 512 + ((jj * 16) ^ ((row & 7) << 4));
        u16x8 v = *(const u16x8*)((const char*)sP + byte);
        *(u16x8*)&gbase[(size_t)row * gstride + jj * 8] = v;
    }
}

// ---------------------------------------------------------------------------
// proj_all: blocks [0,256) = q-projection (swapped: A=WqT d-rows, B=qbin
// i-rows); blocks [256,768) = kv-projection (A=kvbin i-rows, B=WkvT n-rows).
// ---------------------------------------------------------------------------
__global__ __launch_bounds__(512, 1)
void proj_all(const unsigned short* __restrict__ Wt,
              const unsigned short* __restrict__ qbin,
              const unsigned short* __restrict__ kvbin,
              const float* __restrict__ bq, const float* __restrict__ bk,
              const float* __restrict__ bv,
              unsigned short* __restrict__ qb, unsigned short* __restrict__ kb,
              unsigned short* __restrict__ vt)
{
    PIPE_PREAMBLE
    const int bid = blockIdx.x;
    const size_t strideA = EMB, strideB = EMB;
    const unsigned short* Asrc;
    const unsigned short* Bsrc;
    int d0 = 0, i0 = 0, m0 = 0, n0 = 0;
    const bool qrole = (bid < 256);
    if (qrole) {
        const int lid = (bid & 7) * 32 + (bid >> 3);
        d0 = (lid & 3) * 256; i0 = (lid >> 2) * 256;
        Asrc = Wt + (size_t)(d0 + (tid >> 2)) * EMB + scol;
        Bsrc = qbin + (size_t)(i0 + (tid >> 2)) * EMB + scol;
    } else {
        const int b2 = bid - 256;
        const int lid = (b2 & 7) * 64 + (b2 >> 3);
        n0 = (lid & 7) * 256; m0 = (lid >> 3) * 256;
        Asrc = kvbin + (size_t)(m0 + (tid >> 2)) * EMB + scol;
        Bsrc = Wt + (size_t)EMB * EMB + (size_t)(n0 + (tid >> 2)) * EMB + scol;
    }

    pipe_gemm(Asrc, Bsrc, strideA, strideB, EMB / 32, sA, sB, lwave, aoff0, boff0, acc);

    if (qrole) {
        // LDS transpose: row = i-local (wn,n,r), col = d-local (wr,mm,g,c)
#pragma unroll
        for (int mm = 0; mm < 8; mm++) {
            const int colb = wr * 128 + mm * 16 + g * 4;
            const fl4 b4 = *(const fl4*)&bq[d0 + colb];
#pragma unroll
            for (int n = 0; n < 4; n++) {
                const int row = wn * 64 + n * 16 + r;
                u16x4 u;
#pragma unroll
                for (int c = 0; c < 4; c++) u[c] = f2bf(acc[mm][n][c] + b4[c]);
                const int byte = row * 512 + ((colb * 2) ^ ((row & 7) << 4));
                *(u16x4*)((char*)sMem + byte) = u;
            }
        }
        __syncthreads();
        lds_flush_bf16(sMem, qb + (size_t)i0 * EMB + d0, EMB, tid);
    } else {
        const int b = m0 >> 11;                 // batch of this 256-row i-tile
        const int j0l = m0 & 2047;
        if (n0 < 1024) {                        // k-output (block-uniform)
#pragma unroll
            for (int mm = 0; mm < 8; mm++) {
                const int ibase = m0 + wr * 128 + mm * 16 + g * 4;
#pragma unroll
                for (int n = 0; n < 4; n++) {
                    const int col = n0 + wn * 64 + n * 16 + r;
                    const float bb = bk[col];
#pragma unroll
                    for (int c = 0; c < 4; c++)
                        kb[(size_t)(ibase + c) * EMB + col] = f2bf(acc[mm][n][c] + bb);
                }
            }
        } else {                                // v-output: LDS transpose
#pragma unroll
            for (int mm = 0; mm < 8; mm++) {
                const int colb = wr * 128 + mm * 16 + g * 4;
#pragma unroll
                for (int n = 0; n < 4; n++) {
                    const int row = wn * 64 + n * 16 + r;
                    const float bb = bv[n0 - 1024 + row];
                    u16x4 u;
#pragma unroll
                    for (int c = 0; c < 4; c++) u[c] = f2bf(acc[mm][n][c] + bb);
                    const int byte = row * 512 + ((colb * 2) ^ ((row & 7) << 4));
                    *(u16x4*)((char*)sMem + byte) = u;
                }
            }
            __syncthreads();
            lds_flush_bf16(sMem, vt + ((size_t)b * EMB + (n0 - 1024)) * SEQ + j0l,
                           SEQ, tid);
        }
    }
}

// ---------------------------------------------------------------------------
// qk (swapped): A = kb rows (j), B = qb rows (i). P[i][j] = exp2(S*sc) via
// LDS transpose; partial rowsums (16 slots) to Ppart.
// ---------------------------------------------------------------------------
__global__ __launch_bounds__(512, 1)
void qk256_kernel(const unsigned short* __restrict__ qb,
                  const unsigned short* __restrict__ kb,
                  unsigned short* __restrict__ P,
                  float* __restrict__ Ppart)
{
    PIPE_PREAMBLE
    const int bid = blockIdx.x;                 // 512 blocks
    const int lid = (bid & 7) * 64 + (bid >> 3);
    const int b = lid >> 6, jt = (lid >> 3) & 7, it = lid & 7;
    const int j0 = jt * 256, i0 = it * 256;
    const size_t strideA = EMB, strideB = EMB;
    const unsigned short* Ag = kb + (size_t)b * SEQ * EMB;
    const unsigned short* Bg = qb + (size_t)b * SEQ * EMB;
    const unsigned short* Asrc = Ag + (size_t)(j0 + (tid >> 2)) * EMB + scol;
    const unsigned short* Bsrc = Bg + (size_t)(i0 + (tid >> 2)) * EMB + scol;

    pipe_gemm(Asrc, Bsrc, strideA, strideB, EMB / 32, sA, sB, lwave, aoff0, boff0, acc);

    // LDS transpose: row = i-local (wn,n,r), col = j-local (wr,mm,g,c)
    float ps[4] = {0.f, 0.f, 0.f, 0.f};
#pragma unroll
    for (int mm = 0; mm < 8; mm++) {
        const int colb = wr * 128 + mm * 16 + g * 4;
#pragma unroll
        for (int n = 0; n < 4; n++) {
            const int row = wn * 64 + n * 16 + r;
            u16x4 u;
#pragma unroll
            for (int c = 0; c < 4; c++) {
                const float p = exp2f(acc[mm][n][c] * SC2);   // no max-sub: |S|<~6
                ps[n] += p;
                u[c] = f2bf(p);
            }
            const int byte = row * 512 + ((colb * 2) ^ ((row & 7) << 4));
            *(u16x4*)((char*)sMem + byte) = u;
        }
    }
    // partial rowsums: reduce over g (j-direction)
#pragma unroll
    for (int n = 0; n < 4; n++) {
        ps[n] += __shfl_xor(ps[n], 16);
        ps[n] += __shfl_xor(ps[n], 32);
    }
    if (g == 0) {
        const int slot = jt * 2 + wr;
        float* pp = Ppart + (size_t)slot * (BATCH * SEQ) + (size_t)b * SEQ;
#pragma unroll
        for (int n = 0; n < 4; n++)
            pp[i0 + wn * 64 + n * 16 + r] = ps[n];
    }
    __syncthreads();
    unsigned short* Pb = P + (size_t)b * SEQ * SEQ;
    lds_flush_bf16(sMem, Pb + (size_t)i0 * SEQ + j0, SEQ, tid);
}

// ---------------------------------------------------------------------------
// pv (swapped): A = vt rows (d), B = P rows (i). Rowsum finalize fused into
// the prologue. out[i][d] f32 via LDS transpose in two chunks.
// ---------------------------------------------------------------------------
__global__ __launch_bounds__(512, 1)
void pv256_kernel(const unsigned short* __restrict__ P,
                  const unsigned short* __restrict__ vt,
                  const float* __restrict__ Ppart,
                  float* __restrict__ out)
{
    PIPE_PREAMBLE
    const int bid = blockIdx.x;                 // 256 blocks
    const int lid = (bid & 7) * 32 + (bid >> 3);
    const int b = lid >> 5, it = (lid >> 2) & 7, dt = lid & 3;
    const int d0 = dt * 256, i0 = it * 256;
    const size_t strideA = SEQ, strideB = SEQ;
    const unsigned short* Ag = vt + (size_t)b * EMB * SEQ;
    const unsigned short* Bg = P + (size_t)b * SEQ * SEQ;
    const unsigned short* Asrc = Ag + (size_t)(d0 + (tid >> 2)) * SEQ + scol;
    const unsigned short* Bsrc = Bg + (size_t)(i0 + (tid >> 2)) * SEQ + scol;

    // fused rowsum finalize: inv[n] for this thread's 4 owned i-rows
    float inv[4];
#pragma unroll
    for (int n = 0; n < 4; n++) {
        const int row = b * SEQ + i0 + wn * 64 + n * 16 + r;
        float s = 0.f;
#pragma unroll
        for (int slot = 0; slot < 16; slot++)
            s += Ppart[(size_t)slot * (BATCH * SEQ) + row];
        inv[n] = 1.0f / s;
    }

    pipe_gemm(Asrc, Bsrc, strideA, strideB, SEQ / 32, sA, sB, lwave, aoff0, boff0, acc);

    float* ob = out + (size_t)b * SEQ * EMB;
    float* sF = (float*)sMem;   // [256 rows][128 f32] per chunk
#pragma unroll
    for (int h = 0; h < 2; h++) {
        if (wr == h) {
            // row = i-local (wn,n,r), col = d-local within chunk (mm,g,c)
#pragma unroll
            for (int mm = 0; mm < 8; mm++) {
                const int colb = mm * 16 + g * 4;      // 0..127
#pragma unroll
                for (int n = 0; n < 4; n++) {
                    const int row = wn * 64 + n * 16 + r;
                    fl4 o;
#pragma unroll
                    for (int c = 0; c < 4; c++) o[c] = acc[mm][n][c] * inv[n];
                    const int byte = row * 512 + ((colb * 4) ^ ((row & 7) << 4));
                    *(fl4*)((char*)sF + byte) = o;
                }
            }
        }
        __syncthreads();
        {
            const int rowsel = lane >> 5, jj = lane & 31;
#pragma unroll
            for (int itx = 0; itx < 16; ++itx) {
                const int row = itx * 16 + wid * 2 + rowsel;
                const int byte = row * 512 + ((jj * 16) ^ ((row & 7) << 4));
                fl4 v = *(const fl4*)((const char*)sF + byte);
                *(fl4*)&ob[(size_t)(i0 + row) * EMB + d0 + h * 128 + jj * 4] = v;
            }
        }
        if (h == 0) __syncthreads();
    }
}

// ---------------------------------------------------------------------------
extern "C" void kernel_launch(void* const* d_in, const int* in_sizes, int n_in,
                              void* d_out, int out_size, void* d_ws, size_t ws_size,
                              hipStream_t stream)
{
    const float* q_in = (const float*)d_in[0];
    const float* k_v  = (const float*)d_in[1];
    const float* Wq   = (const float*)d_in[2];
    const float* bq   = (const float*)d_in[3];
    const float* Wk   = (const float*)d_in[4];
    const float* bk   = (const float*)d_in[5];
    const float* Wv   = (const float*)d_in[6];
    const float* bv   = (const float*)d_in[7];
    float* out = (float*)d_out;

    // workspace layout (bytes):
    //   qbin  bf16 [8][2048][1024] @ 0      -- dead after proj_all
    //   kvbin bf16 [8][2048][1024] @ 32 MB  -- dead after proj_all
    //   P     bf16 [8][2048][2048] @ 0      -- aliases qbin+kvbin
    //   qb @ 64 MB ; kb @ 96 MB ; vt @ 128 MB ; Wt (WqT|WkT|WvT) @ 160 MB
    //   Ppart f32 [16][16384] @ 166 MB
    char* ws = (char*)d_ws;
    unsigned short* qbin = (unsigned short*)(ws);
    unsigned short* kvbin= (unsigned short*)(ws + (size_t)33554432);
    unsigned short* P    = (unsigned short*)(ws);
    unsigned short* qb   = (unsigned short*)(ws + (size_t)67108864);
    unsigned short* kb   = (unsigned short*)(ws + (size_t)100663296);
    unsigned short* vt   = (unsigned short*)(ws + (size_t)134217728);
    unsigned short* Wt   = (unsigned short*)(ws + (size_t)167772160);
    float*          Ppart= (float*)(ws + (size_t)174063616);

    convert_all<<<4864, 256, 0, stream>>>(q_in, k_v, Wq, Wk, Wv, qbin, kvbin, Wt);
    proj_all<<<768, 512, 0, stream>>>(Wt, qbin, kvbin, bq, bk, bv, qb, kb, vt);
    qk256_kernel<<<512, 512, 0, stream>>>(qb, kb, P, Ppart);
    pv256_kernel<<<256, 512, 0, stream>>>(P, vt, Ppart, out);
}

// Round 9
// 293.153 us; speedup vs baseline: 1.2538x; 1.0289x over previous
//
#include <hip/hip_runtime.h>
#include <hip/hip_bf16.h>

// CrossAttention: q = q_in@Wq+bq; k = k_v@Wk+bk; v = k_v@Wv+bv
// S = q@k^T * EMBED^-0.5 ; P = softmax(S) ; out = P@v
// B=8, I=J=2048, D=1024. All f32 in/out; internal compute bf16 MFMA.

#define BATCH 8
#define SEQ   2048
#define EMB   1024
#define SC2   0.045084222f         // EMB^-0.5 * log2(e)

typedef __attribute__((ext_vector_type(8))) short bf16x8;
typedef __attribute__((ext_vector_type(4))) float f32x4;
typedef __attribute__((ext_vector_type(4))) unsigned short u16x4;
typedef __attribute__((ext_vector_type(8))) unsigned short u16x8;
typedef __attribute__((ext_vector_type(4))) float fl4;

__device__ __forceinline__ unsigned short f2bf(float f) {
    unsigned u = __builtin_bit_cast(unsigned, f);
    unsigned r = u + 0x7fffu + ((u >> 16) & 1u);   // RNE
    return (unsigned short)(r >> 16);
}
__device__ __forceinline__ float bf2f(unsigned short s) {
    return __builtin_bit_cast(float, ((unsigned)s) << 16);
}
__device__ __forceinline__ void gload16(const unsigned short* g, unsigned short* l) {
    __builtin_amdgcn_global_load_lds(
        (const __attribute__((address_space(1))) void*)g,
        (__attribute__((address_space(3))) void*)l, 16, 0, 0);
}

// ---------------------------------------------------------------------------
// convert_all: blocks [0,4096) convert q_in/k_v f32->bf16;
// blocks [4096,4864) convert+transpose Wq|Wk|Wv -> Wt [n][k] bf16.
// ---------------------------------------------------------------------------
__global__ __launch_bounds__(256)
void convert_all(const float* __restrict__ q_in, const float* __restrict__ k_v,
                 const float* __restrict__ Wq, const float* __restrict__ Wk,
                 const float* __restrict__ Wv,
                 unsigned short* __restrict__ qbin, unsigned short* __restrict__ kvbin,
                 unsigned short* __restrict__ Wt)
{
    const int bid = blockIdx.x;
    const int tid = threadIdx.x;
    if (bid < 4096) {
        const size_t N = (size_t)BATCH * SEQ * EMB;
        size_t idx = ((size_t)bid * 256 + tid) * 8;
        const size_t stride = (size_t)4096 * 256 * 8;
        for (; idx < N; idx += stride) {
            fl4 a0 = *(const fl4*)&q_in[idx];
            fl4 a1 = *(const fl4*)&q_in[idx + 4];
            fl4 b0 = *(const fl4*)&k_v[idx];
            fl4 b1 = *(const fl4*)&k_v[idx + 4];
            u16x8 ua, ub;
#pragma unroll
            for (int i = 0; i < 4; i++) {
                ua[i] = f2bf(a0[i]); ua[i + 4] = f2bf(a1[i]);
                ub[i] = f2bf(b0[i]); ub[i + 4] = f2bf(b1[i]);
            }
            *(u16x8*)&qbin[idx] = ua;
            *(u16x8*)&kvbin[idx] = ub;
        }
    } else {
        const int b2 = bid - 4096;              // 768 blocks
        const int wsel = b2 >> 8, rest = b2 & 255;
        const float* W = (wsel == 0) ? Wq : (wsel == 1) ? Wk : Wv;
        unsigned short* O = Wt + (size_t)wsel * EMB * EMB;
        const int k0 = (rest >> 4) * 64;
        const int n0 = (rest & 15) * 64;
        __shared__ unsigned short l[64 * 65];
#pragma unroll
        for (int it = 0; it < 16; it++) {
            const int lin = it * 256 + tid;
            const int k = lin >> 6, n = lin & 63;
            l[n * 65 + k] = f2bf(W[(size_t)(k0 + k) * EMB + n0 + n]);
        }
        __syncthreads();
#pragma unroll
        for (int it = 0; it < 16; it++) {
            const int lin = it * 256 + tid;
            const int n = lin >> 6, k = lin & 63;
            O[(size_t)(n0 + n) * EMB + k0 + k] = l[n * 65 + k];
        }
    }
}

// ---------------------------------------------------------------------------
// Shared deep-pipelined 256x256 GEMM core (BK=32, 8 waves, 4-slot LDS ring).
// LDS tile [256 rows][4 col16] bf16, COLUMN-SWIZZLED (r8): (row R, col16 c)
// stored at c' = c ^ ((R>>1)&3); linear gload_lds dest + pre-permuted global
// source + swizzled frag reads (rule #21). All 32 banks covered per b128.
// r9: SINGLE barrier per tile; no forced lgkmcnt(0) -- ds_reads are C-level
// loads, compiler emits fine-grained counted lgkmcnt so read latency hides
// under the MFMA clusters. Barrier audit: slot-s reads complete before each
// wave's closing barrier (MFMA consumption forces waits); T+2 stage cannot
// outrun T-2 readers (two barriers back). vmcnt(4) at tile end = T+1's
// stages landed (proven r4 ring discipline).
// ---------------------------------------------------------------------------
__device__ __forceinline__ void stageT(const unsigned short* lanebase, size_t rstride,
                                       unsigned short* lwave) {
#pragma unroll
    for (int i = 0; i < 2; i++)
        gload16(lanebase + (size_t)(i * 128) * rstride, lwave + i * 4096);
}

#define PIPE_TILE(SLOT, DO_STAGE, STAGE_A_BASE, STAGE_A_LDS, STAGE_B_BASE, STAGE_B_LDS) \
    {                                                                           \
        const unsigned short* pa = &sA[SLOT][0];                                \
        const unsigned short* pb = &sB[SLOT][0];                                \
        bf16x8 a0 = *(bf16x8*)&pa[aoff0];                                       \
        bf16x8 a1 = *(bf16x8*)&pa[aoff0 + 512];                                 \
        bf16x8 a2 = *(bf16x8*)&pa[aoff0 + 1024];                                \
        bf16x8 a3 = *(bf16x8*)&pa[aoff0 + 1536];                                \
        bf16x8 a4 = *(bf16x8*)&pa[aoff0 + 2048];                                \
        bf16x8 a5 = *(bf16x8*)&pa[aoff0 + 2560];                                \
        bf16x8 a6 = *(bf16x8*)&pa[aoff0 + 3072];                                \
        bf16x8 a7 = *(bf16x8*)&pa[aoff0 + 3584];                                \
        bf16x8 bv0 = *(bf16x8*)&pb[boff0];                                      \
        bf16x8 bv1 = *(bf16x8*)&pb[boff0 + 512];                                \
        bf16x8 bv2 = *(bf16x8*)&pb[boff0 + 1024];                               \
        bf16x8 bv3 = *(bf16x8*)&pb[boff0 + 1536];                               \
        if (DO_STAGE) stageT(STAGE_A_BASE, strideA, STAGE_A_LDS);               \
        __builtin_amdgcn_s_setprio(1);                                          \
        acc[0][0] = __builtin_amdgcn_mfma_f32_16x16x32_bf16(a0, bv0, acc[0][0], 0, 0, 0); \
        acc[0][1] = __builtin_amdgcn_mfma_f32_16x16x32_bf16(a0, bv1, acc[0][1], 0, 0, 0); \
        acc[0][2] = __builtin_amdgcn_mfma_f32_16x16x32_bf16(a0, bv2, acc[0][2], 0, 0, 0); \
        acc[0][3] = __builtin_amdgcn_mfma_f32_16x16x32_bf16(a0, bv3, acc[0][3], 0, 0, 0); \
        acc[1][0] = __builtin_amdgcn_mfma_f32_16x16x32_bf16(a1, bv0, acc[1][0], 0, 0, 0); \
        acc[1][1] = __builtin_amdgcn_mfma_f32_16x16x32_bf16(a1, bv1, acc[1][1], 0, 0, 0); \
        acc[1][2] = __builtin_amdgcn_mfma_f32_16x16x32_bf16(a1, bv2, acc[1][2], 0, 0, 0); \
        acc[1][3] = __builtin_amdgcn_mfma_f32_16x16x32_bf16(a1, bv3, acc[1][3], 0, 0, 0); \
        acc[2][0] = __builtin_amdgcn_mfma_f32_16x16x32_bf16(a2, bv0, acc[2][0], 0, 0, 0); \
        acc[2][1] = __builtin_amdgcn_mfma_f32_16x16x32_bf16(a2, bv1, acc[2][1], 0, 0, 0); \
        acc[2][2] = __builtin_amdgcn_mfma_f32_16x16x32_bf16(a2, bv2, acc[2][2], 0, 0, 0); \
        acc[2][3] = __builtin_amdgcn_mfma_f32_16x16x32_bf16(a2, bv3, acc[2][3], 0, 0, 0); \
        acc[3][0] = __builtin_amdgcn_mfma_f32_16x16x32_bf16(a3, bv0, acc[3][0], 0, 0, 0); \
        acc[3][1] = __builtin_amdgcn_mfma_f32_16x16x32_bf16(a3, bv1, acc[3][1], 0, 0, 0); \
        acc[3][2] = __builtin_amdgcn_mfma_f32_16x16x32_bf16(a3, bv2, acc[3][2], 0, 0, 0); \
        acc[3][3] = __builtin_amdgcn_mfma_f32_16x16x32_bf16(a3, bv3, acc[3][3], 0, 0, 0); \
        __builtin_amdgcn_s_setprio(0);                                          \
        if (DO_STAGE) stageT(STAGE_B_BASE, strideB, STAGE_B_LDS);               \
        __builtin_amdgcn_s_setprio(1);                                          \
        acc[4][0] = __builtin_amdgcn_mfma_f32_16x16x32_bf16(a4, bv0, acc[4][0], 0, 0, 0); \
        acc[4][1] = __builtin_amdgcn_mfma_f32_16x16x32_bf16(a4, bv1, acc[4][1], 0, 0, 0); \
        acc[4][2] = __builtin_amdgcn_mfma_f32_16x16x32_bf16(a4, bv2, acc[4][2], 0, 0, 0); \
        acc[4][3] = __builtin_amdgcn_mfma_f32_16x16x32_bf16(a4, bv3, acc[4][3], 0, 0, 0); \
        acc[5][0] = __builtin_amdgcn_mfma_f32_16x16x32_bf16(a5, bv0, acc[5][0], 0, 0, 0); \
        acc[5][1] = __builtin_amdgcn_mfma_f32_16x16x32_bf16(a5, bv1, acc[5][1], 0, 0, 0); \
        acc[5][2] = __builtin_amdgcn_mfma_f32_16x16x32_bf16(a5, bv2, acc[5][2], 0, 0, 0); \
        acc[5][3] = __builtin_amdgcn_mfma_f32_16x16x32_bf16(a5, bv3, acc[5][3], 0, 0, 0); \
        acc[6][0] = __builtin_amdgcn_mfma_f32_16x16x32_bf16(a6, bv0, acc[6][0], 0, 0, 0); \
        acc[6][1] = __builtin_amdgcn_mfma_f32_16x16x32_bf16(a6, bv1, acc[6][1], 0, 0, 0); \
        acc[6][2] = __builtin_amdgcn_mfma_f32_16x16x32_bf16(a6, bv2, acc[6][2], 0, 0, 0); \
        acc[6][3] = __builtin_amdgcn_mfma_f32_16x16x32_bf16(a6, bv3, acc[6][3], 0, 0, 0); \
        acc[7][0] = __builtin_amdgcn_mfma_f32_16x16x32_bf16(a7, bv0, acc[7][0], 0, 0, 0); \
        acc[7][1] = __builtin_amdgcn_mfma_f32_16x16x32_bf16(a7, bv1, acc[7][1], 0, 0, 0); \
        acc[7][2] = __builtin_amdgcn_mfma_f32_16x16x32_bf16(a7, bv2, acc[7][2], 0, 0, 0); \
        acc[7][3] = __builtin_amdgcn_mfma_f32_16x16x32_bf16(a7, bv3, acc[7][3], 0, 0, 0); \
        __builtin_amdgcn_s_setprio(0);                                          \
        asm volatile("s_waitcnt vmcnt(4)" ::: "memory");                        \
        __builtin_amdgcn_s_barrier();                                           \
        __builtin_amdgcn_sched_barrier(0);                                      \
    }

__device__ __forceinline__ void pipe_gemm(
    const unsigned short* __restrict__ Asrc,
    const unsigned short* __restrict__ Bsrc,
    const size_t strideA, const size_t strideB, const int NT,
    unsigned short (*sA)[8192], unsigned short (*sB)[8192],
    const int lwave, const int aoff0, const int boff0,
    f32x4 acc[8][4])
{
    stageT(Asrc, strideA, &sA[0][lwave]);
    stageT(Bsrc, strideB, &sB[0][lwave]);
    stageT(Asrc + 32, strideA, &sA[1][lwave]);
    stageT(Bsrc + 32, strideB, &sB[1][lwave]);
    asm volatile("s_waitcnt vmcnt(4)" ::: "memory");
    __builtin_amdgcn_s_barrier();
    __builtin_amdgcn_sched_barrier(0);

    for (int T = 0; T < NT; ++T) {
        const int s = T & 3;
        const int doStage = (T + 2 < NT);
        const int s2 = (T + 2) & 3;
        PIPE_TILE(s, doStage, Asrc + (T + 2) * 32, &sA[s2][lwave],
                  Bsrc + (T + 2) * 32, &sB[s2][lwave]);
    }
}

// scol: swizzled source column (elems). Lane lands at LDS (R=tid>>2, c'=tid&3);
// it must fetch global col c = c' ^ ((R>>1)&3) = (tid&3) ^ ((tid>>3)&3).
// Frag read col for (row, g): c' = g ^ ((row>>1)&3); row>>1 bits reduce to
// (r>>1)&3 uniformly (wr*128, wn*64, mm*16, n*16 all vanish mod 4 after >>1).
#define PIPE_PREAMBLE                                                     \
    __shared__ unsigned short sMem[65536];  /* 128 KB */                  \
    unsigned short (*sA)[8192] = (unsigned short (*)[8192])sMem;          \
    unsigned short (*sB)[8192] = (unsigned short (*)[8192])(sMem + 32768);\
    const int tid = threadIdx.x, lane = tid & 63;                         \
    const int wid = tid >> 6, wr = wid >> 2, wn = wid & 3;                \
    const int r = lane & 15, g = lane >> 4;                               \
    const int lwave = (wid << 9);                                         \
    const int scol = ((tid & 3) ^ ((tid >> 3) & 3)) * 8;                  \
    const int gsw = (g ^ ((r >> 1) & 3)) * 8;                             \
    const int aoff0 = (wr * 128 + r) * 32 + gsw;                          \
    const int boff0 = (wn * 64 + r) * 32 + gsw;                           \
    f32x4 acc[8][4];                                                      \
    _Pragma("unroll") for (int i_ = 0; i_ < 8; i_++)                      \
    _Pragma("unroll") for (int j_ = 0; j_ < 4; j_++) acc[i_][j_] = (f32x4)0.0f;

// Coalesced flush of a [256 row][512 B] swizzled LDS tile to global.
__device__ __forceinline__ void lds_flush_bf16(const unsigned short* sP,
                                               unsigned short* gbase,
                                               size_t gstride, int tid)
{
    const int lane = tid & 63, wv = tid >> 6;
    const int rowsel = lane >> 5, jj = lane & 31;
#pragma unroll
    for (int it = 0; it < 16; ++it) {
        const int row = it * 16 + wv * 2 + rowsel;
        const int byte = row * 512 + ((jj * 16) ^ ((row & 7) << 4));
        u16x8 v = *(const u16x8*)((const char*)sP + byte);
        *(u16x8*)&gbase[(size_t)row * gstride + jj * 8] = v;
    }
}

// ---------------------------------------------------------------------------
// proj_all: blocks [0,256) = q-projection (swapped: A=WqT d-rows, B=qbin
// i-rows); blocks [256,768) = kv-projection (A=kvbin i-rows, B=WkvT n-rows).
// ---------------------------------------------------------------------------
__global__ __launch_bounds__(512, 1)
void proj_all(const unsigned short* __restrict__ Wt,
              const unsigned short* __restrict__ qbin,
              const unsigned short* __restrict__ kvbin,
              const float* __restrict__ bq, const float* __restrict__ bk,
              const float* __restrict__ bv,
              unsigned short* __restrict__ qb, unsigned short* __restrict__ kb,
              unsigned short* __restrict__ vt)
{
    PIPE_PREAMBLE
    const int bid = blockIdx.x;
    const size_t strideA = EMB, strideB = EMB;
    const unsigned short* Asrc;
    const unsigned short* Bsrc;
    int d0 = 0, i0 = 0, m0 = 0, n0 = 0;
    const bool qrole = (bid < 256);
    if (qrole) {
        const int lid = (bid & 7) * 32 + (bid >> 3);
        d0 = (lid & 3) * 256; i0 = (lid >> 2) * 256;
        Asrc = Wt + (size_t)(d0 + (tid >> 2)) * EMB + scol;
        Bsrc = qbin + (size_t)(i0 + (tid >> 2)) * EMB + scol;
    } else {
        const int b2 = bid - 256;
        const int lid = (b2 & 7) * 64 + (b2 >> 3);
        n0 = (lid & 7) * 256; m0 = (lid >> 3) * 256;
        Asrc = kvbin + (size_t)(m0 + (tid >> 2)) * EMB + scol;
        Bsrc = Wt + (size_t)EMB * EMB + (size_t)(n0 + (tid >> 2)) * EMB + scol;
    }

    pipe_gemm(Asrc, Bsrc, strideA, strideB, EMB / 32, sA, sB, lwave, aoff0, boff0, acc);

    if (qrole) {
        // LDS transpose: row = i-local (wn,n,r), col = d-local (wr,mm,g,c)
#pragma unroll
        for (int mm = 0; mm < 8; mm++) {
            const int colb = wr * 128 + mm * 16 + g * 4;
            const fl4 b4 = *(const fl4*)&bq[d0 + colb];
#pragma unroll
            for (int n = 0; n < 4; n++) {
                const int row = wn * 64 + n * 16 + r;
                u16x4 u;
#pragma unroll
                for (int c = 0; c < 4; c++) u[c] = f2bf(acc[mm][n][c] + b4[c]);
                const int byte = row * 512 + ((colb * 2) ^ ((row & 7) << 4));
                *(u16x4*)((char*)sMem + byte) = u;
            }
        }
        __syncthreads();
        lds_flush_bf16(sMem, qb + (size_t)i0 * EMB + d0, EMB, tid);
    } else {
        const int b = m0 >> 11;                 // batch of this 256-row i-tile
        const int j0l = m0 & 2047;
        if (n0 < 1024) {                        // k-output (block-uniform)
#pragma unroll
            for (int mm = 0; mm < 8; mm++) {
                const int ibase = m0 + wr * 128 + mm * 16 + g * 4;
#pragma unroll
                for (int n = 0; n < 4; n++) {
                    const int col = n0 + wn * 64 + n * 16 + r;
                    const float bb = bk[col];
#pragma unroll
                    for (int c = 0; c < 4; c++)
                        kb[(size_t)(ibase + c) * EMB + col] = f2bf(acc[mm][n][c] + bb);
                }
            }
        } else {                                // v-output: LDS transpose
#pragma unroll
            for (int mm = 0; mm < 8; mm++) {
                const int colb = wr * 128 + mm * 16 + g * 4;
#pragma unroll
                for (int n = 0; n < 4; n++) {
                    const int row = wn * 64 + n * 16 + r;
                    const float bb = bv[n0 - 1024 + row];
                    u16x4 u;
#pragma unroll
                    for (int c = 0; c < 4; c++) u[c] = f2bf(acc[mm][n][c] + bb);
                    const int byte = row * 512 + ((colb * 2) ^ ((row & 7) << 4));
                    *(u16x4*)((char*)sMem + byte) = u;
                }
            }
            __syncthreads();
            lds_flush_bf16(sMem, vt + ((size_t)b * EMB + (n0 - 1024)) * SEQ + j0l,
                           SEQ, tid);
        }
    }
}

// ---------------------------------------------------------------------------
// qk (swapped): A = kb rows (j), B = qb rows (i). P[i][j] = exp2(S*sc) via
// LDS transpose; partial rowsums (16 slots) to Ppart.
// ---------------------------------------------------------------------------
__global__ __launch_bounds__(512, 1)
void qk256_kernel(const unsigned short* __restrict__ qb,
                  const unsigned short* __restrict__ kb,
                  unsigned short* __restrict__ P,
                  float* __restrict__ Ppart)
{
    PIPE_PREAMBLE
    const int bid = blockIdx.x;                 // 512 blocks
    const int lid = (bid & 7) * 64 + (bid >> 3);
    const int b = lid >> 6, jt = (lid >> 3) & 7, it = lid & 7;
    const int j0 = jt * 256, i0 = it * 256;
    const size_t strideA = EMB, strideB = EMB;
    const unsigned short* Ag = kb + (size_t)b * SEQ * EMB;
    const unsigned short* Bg = qb + (size_t)b * SEQ * EMB;
    const unsigned short* Asrc = Ag + (size_t)(j0 + (tid >> 2)) * EMB + scol;
    const unsigned short* Bsrc = Bg + (size_t)(i0 + (tid >> 2)) * EMB + scol;

    pipe_gemm(Asrc, Bsrc, strideA, strideB, EMB / 32, sA, sB, lwave, aoff0, boff0, acc);

    // LDS transpose: row = i-local (wn,n,r), col = j-local (wr,mm,g,c)
    float ps[4] = {0.f, 0.f, 0.f, 0.f};
#pragma unroll
    for (int mm = 0; mm < 8; mm++) {
        const int colb = wr * 128 + mm * 16 + g * 4;
#pragma unroll
        for (int n = 0; n < 4; n++) {
            const int row = wn * 64 + n * 16 + r;
            u16x4 u;
#pragma unroll
            for (int c = 0; c < 4; c++) {
                const float p = exp2f(acc[mm][n][c] * SC2);   // no max-sub: |S|<~6
                ps[n] += p;
                u[c] = f2bf(p);
            }
            const int byte = row * 512 + ((colb * 2) ^ ((row & 7) << 4));
            *(u16x4*)((char*)sMem + byte) = u;
        }
    }
    // partial rowsums: reduce over g (j-direction)
#pragma unroll
    for (int n = 0; n < 4; n++) {
        ps[n] += __shfl_xor(ps[n], 16);
        ps[n] += __shfl_xor(ps[n], 32);
    }
    if (g == 0) {
        const int slot = jt * 2 + wr;
        float* pp = Ppart + (size_t)slot * (BATCH * SEQ) + (size_t)b * SEQ;
#pragma unroll
        for (int n = 0; n < 4; n++)
            pp[i0 + wn * 64 + n * 16 + r] = ps[n];
    }
    __syncthreads();
    unsigned short* Pb = P + (size_t)b * SEQ * SEQ;
    lds_flush_bf16(sMem, Pb + (size_t)i0 * SEQ + j0, SEQ, tid);
}

// ---------------------------------------------------------------------------
// pv (swapped): A = vt rows (d), B = P rows (i). Rowsum finalize fused into
// the prologue. out[i][d] f32 via LDS transpose in two chunks.
// ---------------------------------------------------------------------------
__global__ __launch_bounds__(512, 1)
void pv256_kernel(const unsigned short* __restrict__ P,
                  const unsigned short* __restrict__ vt,
                  const float* __restrict__ Ppart,
                  float* __restrict__ out)
{
    PIPE_PREAMBLE
    const int bid = blockIdx.x;                 // 256 blocks
    const int lid = (bid & 7) * 32 + (bid >> 3);
    const int b = lid >> 5, it = (lid >> 2) & 7, dt = lid & 3;
    const int d0 = dt * 256, i0 = it * 256;
    const size_t strideA = SEQ, strideB = SEQ;
    const unsigned short* Ag = vt + (size_t)b * EMB * SEQ;
    const unsigned short* Bg = P + (size_t)b * SEQ * SEQ;
    const unsigned short* Asrc = Ag + (size_t)(d0 + (tid >> 2)) * SEQ + scol;
    const unsigned short* Bsrc = Bg + (size_t)(i0 + (tid >> 2)) * SEQ + scol;

    // fused rowsum finalize: inv[n] for this thread's 4 owned i-rows
    float inv[4];
#pragma unroll
    for (int n = 0; n < 4; n++) {
        const int row = b * SEQ + i0 + wn * 64 + n * 16 + r;
        float s = 0.f;
#pragma unroll
        for (int slot = 0; slot < 16; slot++)
            s += Ppart[(size_t)slot * (BATCH * SEQ) + row];
        inv[n] = 1.0f / s;
    }

    pipe_gemm(Asrc, Bsrc, strideA, strideB, SEQ / 32, sA, sB, lwave, aoff0, boff0, acc);

    float* ob = out + (size_t)b * SEQ * EMB;
    float* sF = (float*)sMem;   // [256 rows][128 f32] per chunk
#pragma unroll
    for (int h = 0; h < 2; h++) {
        if (wr == h) {
            // row = i-local (wn,n,r), col = d-local within chunk (mm,g,c)
#pragma unroll
            for (int mm = 0; mm < 8; mm++) {
                const int colb = mm * 16 + g * 4;      // 0..127
#pragma unroll
                for (int n = 0; n < 4; n++) {
                    const int row = wn * 64 + n * 16 + r;
                    fl4 o;
#pragma unroll
                    for (int c = 0; c < 4; c++) o[c] = acc[mm][n][c] * inv[n];
                    const int byte = row * 512 + ((colb * 4) ^ ((row & 7) << 4));
                    *(fl4*)((char*)sF + byte) = o;
                }
            }
        }
        __syncthreads();
        {
            const int rowsel = lane >> 5, jj = lane & 31;
#pragma unroll
            for (int itx = 0; itx < 16; ++itx) {
                const int row = itx * 16 + wid * 2 + rowsel;
                const int byte = row * 512 + ((jj * 16) ^ ((row & 7) << 4));
                fl4 v = *(const fl4*)((const char*)sF + byte);
                *(fl4*)&ob[(size_t)(i0 + row) * EMB + d0 + h * 128 + jj * 4] = v;
            }
        }
        if (h == 0) __syncthreads();
    }
}

// ---------------------------------------------------------------------------
extern "C" void kernel_launch(void* const* d_in, const int* in_sizes, int n_in,
                              void* d_out, int out_size, void* d_ws, size_t ws_size,
                              hipStream_t stream)
{
    const float* q_in = (const float*)d_in[0];
    const float* k_v  = (const float*)d_in[1];
    const float* Wq   = (const float*)d_in[2];
    const float* bq   = (const float*)d_in[3];
    const float* Wk   = (const float*)d_in[4];
    const float* bk   = (const float*)d_in[5];
    const float* Wv   = (const float*)d_in[6];
    const float* bv   = (const float*)d_in[7];
    float* out = (float*)d_out;

    // workspace layout (bytes):
    //   qbin  bf16 [8][2048][1024] @ 0      -- dead after proj_all
    //   kvbin bf16 [8][2048][1024] @ 32 MB  -- dead after proj_all
    //   P     bf16 [8][2048][2048] @ 0      -- aliases qbin+kvbin
    //   qb @ 64 MB ; kb @ 96 MB ; vt @ 128 MB ; Wt (WqT|WkT|WvT) @ 160 MB
    //   Ppart f32 [16][16384] @ 166 MB
    char* ws = (char*)d_ws;
    unsigned short* qbin = (unsigned short*)(ws);
    unsigned short* kvbin= (unsigned short*)(ws + (size_t)33554432);
    unsigned short* P    = (unsigned short*)(ws);
    unsigned short* qb   = (unsigned short*)(ws + (size_t)67108864);
    unsigned short* kb   = (unsigned short*)(ws + (size_t)100663296);
    unsigned short* vt   = (unsigned short*)(ws + (size_t)134217728);
    unsigned short* Wt   = (unsigned short*)(ws + (size_t)167772160);
    float*          Ppart= (float*)(ws + (size_t)174063616);

    convert_all<<<4864, 256, 0, stream>>>(q_in, k_v, Wq, Wk, Wv, qbin, kvbin, Wt);
    proj_all<<<768, 512, 0, stream>>>(Wt, qbin, kvbin, bq, bk, bv, qb, kb, vt);
    qk256_kernel<<<512, 512, 0, stream>>>(qb, kb, P, Ppart);
    pv256_kernel<<<256, 512, 0, stream>>>(P, vt, Ppart, out);
}